// Round 7
// baseline (1268.339 us; speedup 1.0000x reference)
//
#include <hip/hip_runtime.h>
#include <hip/hip_bf16.h>
#include <math.h>

#define N_NODES 100000
#define N_PAD   100096   // multiple of 256
#define N_EDGES 400000
#define IN_DIM  100
#define D       200
#define DP      208      // j padded to 13*16
#define KP      224      // k padded to 7*32
#define NUM_STEPS 4

// Truncated half-tile: 3 gates x (6 full t-blocks * 512 + t6 kq0 slice 128) = 9600
// shorts + 128 pad shorts (1216 x 16B chunks).
#define HALF_SHORTS   9728
#define GCAP          512          // per-wave edge-index LDS capacity in gather kernel
#define WCHUNKS_PER_SJT 2432       // 2 halves * 1216 chunks
#define WCONV_BLOCKS  494          // 4*13*2432 / 256

typedef __attribute__((ext_vector_type(8))) short bfrag;   // 8 bf16 (4 VGPRs)
typedef __attribute__((ext_vector_type(4))) float facc;    // 4 fp32

// weights, per-(step,jt) contiguous TRUNCATED tile: [s][jt][half2][gg3][t-compact]
// Layout is EXACT MFMA fragment order -> waves load bv fragments directly from
// global (L2-resident, 2 MB); no LDS staging needed.
__device__ short g_Wall[NUM_STEPS * 13 * 2 * HALF_SHORTS];
__device__ float g_bias[6 * DP];

__device__ __forceinline__ float fast_sigmoid(float x) {
    return __builtin_amdgcn_rcpf(1.0f + __expf(-x));
}
__device__ __forceinline__ float fast_tanh(float x) {
    return 2.0f * __builtin_amdgcn_rcpf(1.0f + __expf(-2.0f * x)) - 1.0f;
}
__device__ __forceinline__ float bf2f(short u) {
    unsigned int x = ((unsigned int)(unsigned short)u) << 16;
    return __uint_as_float(x);
}

// ---------------- weight permute + Wc-fold + bias, all in one kernel ----------------
// Compact layout per (s,jt,half): gate gg in 0..2 at gg*3200 shorts:
//   t<6: gg*3200 + t*512 + lane*8      (lane 0..63)
//   t=6: gg*3200 + 3072 + l*8          (l 0..15, kq=0 slice only; k>=200 is dead: A-side zero)
// chunks 1200..1215 of each half are zero padding.
__global__ __launch_bounds__(256) void wconv_kernel(const float* __restrict__ W,
                                                    const float* __restrict__ w_ih,
                                                    const float* __restrict__ w_hh,
                                                    const float* __restrict__ b_ih,
                                                    const float* __restrict__ b_hh) {
    if (blockIdx.x >= WCONV_BLOCKS) {
        int idx = (blockIdx.x - WCONV_BLOCKS) * 256 + threadIdx.x;
        if (idx < 6 * DP) {
            int g = idx / DP, j = idx % DP;
            float v = 0.0f;
            if (j < D) v = (g < 3) ? b_ih[g * 200 + j] : b_hh[(g - 3) * 200 + j];
            g_bias[idx] = v;
        }
        return;
    }
    int idx = blockIdx.x * 256 + threadIdx.x;   // chunk id < 4*13*2432 = 126464
    short* out = g_Wall + (size_t)idx * 8;
    int s    = idx / (13 * WCHUNKS_PER_SJT);
    int rem  = idx % (13 * WCHUNKS_PER_SJT);
    int jt   = rem / WCHUNKS_PER_SJT;
    int r2   = rem % WCHUNKS_PER_SJT;
    int half = r2 / 1216;
    int c    = r2 % 1216;
    if (c >= 1200) {                       // pad chunks: store zeros
        #pragma unroll
        for (int i = 0; i < 8; ++i) out[i] = 0;
        return;
    }
    int gg = c / 400, cc = c % 400;
    int t  = (cc < 384) ? (cc >> 6) : 6;
    int l  = (cc < 384) ? (cc & 63) : (cc - 384);
    int g  = half * 3 + gg;
    int j  = jt * 16 + (l & 15);
    int k0 = t * 32 + (l >> 4) * 8;
    float vals[8];
    if (g < 3) {
        // fold: vals[i] = dot(w_ih[g*200+j], W[s][k0+i])
        const float* wr = (j < D) ? &w_ih[(size_t)(g * 200 + j) * D] : nullptr;
        #pragma unroll
        for (int i = 0; i < 8; ++i) vals[i] = 0.0f;
        if (wr) {
            #pragma unroll
            for (int i = 0; i < 8; ++i) {
                int k = k0 + i;
                if (k < D) {
                    const float* Wr = &W[(size_t)s * D * D + (size_t)k * D];
                    float acc = 0.0f;
                    #pragma unroll 4
                    for (int tt = 0; tt < D; ++tt) acc += wr[tt] * Wr[tt];
                    vals[i] = acc;
                }
            }
        }
    } else {
        #pragma unroll
        for (int i = 0; i < 8; ++i) {
            int k = k0 + i;
            vals[i] = (j < D && k < D) ? w_hh[((size_t)(g - 3) * 200 + j) * D + k] : 0.0f;
        }
    }
    #pragma unroll
    for (int i = 0; i < 8; ++i) {
        __hip_bfloat16 b = __float2bfloat16(vals[i]);
        out[i] = *reinterpret_cast<short*>(&b);
    }
}

// ---------------- pad: h[:, :100] = bf16(x), rest 0 ----------------
__global__ void pad_kernel(const float* __restrict__ x, __hip_bfloat16* __restrict__ h) {
    int idx = blockIdx.x * 256 + threadIdx.x;   // N_PAD*KP exact multiple of 256
    int n = idx / KP, c = idx % KP;
    float v = (n < N_NODES && c < IN_DIM) ? x[n * IN_DIM + c] : 0.0f;
    h[idx] = __float2bfloat16(v);
}

// ---------------- CSR build ----------------
__global__ void count_kernel(const int* __restrict__ dst, int* __restrict__ cnt) {
    int e = blockIdx.x * blockDim.x + threadIdx.x;
    if (e < N_EDGES) atomicAdd(&cnt[dst[e]], 1);
}

#define SCAN_B 1024
#define NB_SCAN ((N_NODES + SCAN_B - 1) / SCAN_B)   // 98
__global__ __launch_bounds__(SCAN_B) void scan1(const int* __restrict__ cnt,
                                                int* __restrict__ incl, int* __restrict__ bsum) {
    __shared__ int ws[16];
    int i = blockIdx.x * SCAN_B + threadIdx.x;
    int lane = threadIdx.x & 63, wid = threadIdx.x >> 6;
    int v = (i < N_NODES) ? cnt[i] : 0;
    int s = v;
    #pragma unroll
    for (int o = 1; o < 64; o <<= 1) {
        int t = __shfl_up(s, o, 64);
        if (lane >= o) s += t;
    }
    if (lane == 63) ws[wid] = s;
    __syncthreads();
    if (wid == 0) {
        int t = (lane < 16) ? ws[lane] : 0;
        #pragma unroll
        for (int o = 1; o < 16; o <<= 1) {
            int u = __shfl_up(t, o, 64);
            if (lane >= o) t += u;
        }
        if (lane < 16) ws[lane] = t;
    }
    __syncthreads();
    if (wid > 0) s += ws[wid - 1];
    if (i < N_NODES) incl[i] = s;
    if (threadIdx.x == SCAN_B - 1) bsum[blockIdx.x] = s;
}
__global__ void scan3(const int* __restrict__ cnt, const int* __restrict__ incl,
                      const int* __restrict__ bsum, int* __restrict__ off,
                      int* __restrict__ cursor) {
    __shared__ int sh[128];
    if (threadIdx.x < 128) sh[threadIdx.x] = (threadIdx.x < NB_SCAN) ? bsum[threadIdx.x] : 0;
    __syncthreads();
    for (int o = 1; o < 128; o <<= 1) {
        int t = (threadIdx.x >= o && threadIdx.x < 128) ? sh[threadIdx.x - o] : 0;
        __syncthreads();
        if (threadIdx.x < 128) sh[threadIdx.x] += t;
        __syncthreads();
    }
    int i = blockIdx.x * blockDim.x + threadIdx.x;
    if (i < N_NODES) {
        int b = i / SCAN_B;
        int pre = b ? sh[b - 1] : 0;
        int v = incl[i] - cnt[i] + pre;
        off[i] = v; cursor[i] = v;
    }
    if (i == 0) off[N_NODES] = N_EDGES;
}
__global__ void fill_kernel(const int* __restrict__ src, const int* __restrict__ dst,
                            int* __restrict__ cursor, int* __restrict__ esrc) {
    int e = blockIdx.x * blockDim.x + threadIdx.x;
    if (e < N_EDGES) {
        int pos = atomicAdd(&cursor[dst[e]], 1);
        esrc[pos] = src[e];
    }
}

// B-fragment read from a truncated half (GLOBAL pointer; layout is fragment-exact).
// t is compile-time (unrolled loops). t=6, lanes kq>=1: k>=200 where A-side is
// structurally zero -> supply zeros (NaN-safe).
__device__ __forceinline__ bfrag bv_load(const short* Bcur, int g, int t, int lane) {
    if (t < 6) return *(const bfrag*)(Bcur + g * 3200 + t * 512 + lane * 8);
    bfrag z;
    #pragma unroll
    for (int i = 0; i < 8; ++i) z[i] = 0;
    if (lane < 16) z = *(const bfrag*)(Bcur + g * 3200 + 3072 + lane * 8);
    return z;
}

// ---------------- gather/aggregate kernel ----------------
// Latency/occupancy-bound (v3/v4 evidence: BW scales with resident waves). v6: 8 rows
// per wave, grid 3128, GCAP 512 -> 8 KB LDS/block; streams through the 32-wave/CU cap.
__global__ __launch_bounds__(256) void gather_kernel(const __hip_bfloat16* __restrict__ hcur,
                                                     __hip_bfloat16* __restrict__ Ascr,
                                                     const int* __restrict__ off,
                                                     const int* __restrict__ esrc) {
    __shared__ int EIdxAll[4 * GCAP];   // 8192 B
    int tid = threadIdx.x;
    int lane = tid & 63, wave = tid >> 6;
    int wbase = blockIdx.x * 32 + wave * 8;
    int* EIdx = EIdxAll + wave * GCAP;

    // prefetch this wave's contiguous esrc slice (CSR rows are contiguous)
    int nlo = wbase < N_NODES ? wbase : N_NODES;
    int nhi = (wbase + 8) < N_NODES ? (wbase + 8) : N_NODES;
    int lo = off[nlo];
    int cntw = off[nhi] - lo;
    bool use_lds = (cntw <= GCAP);
    if (use_lds)
        for (int i = lane; i < cntw; i += 64) EIdx[i] = esrc[lo + i];

    int r4 = lane >> 4;              // row-in-flight 0..3
    int ck = lane & 15;              // 16B chunk id (this lane also covers ck+16)
    int colA = ck * 8;
    int colB = colA + 128;           // (ck+16)*8
    bool sumB = (ck < 9);            // chunks 16..24 carry data (cols < 200)
    #pragma unroll
    for (int it = 0; it < 2; ++it) {
        int rr = it * 4 + r4;
        int n = wbase + rr;
        float a[8] = {0, 0, 0, 0, 0, 0, 0, 0};
        float b[8] = {0, 0, 0, 0, 0, 0, 0, 0};
        if (n < N_NODES) {
            int e0 = off[n] - lo, e1 = off[n + 1] - lo;
            int nb = (e1 - e0 + 3) >> 2;
            for (int bq = 0; bq < nb; ++bq) {
                int eb = e0 + bq * 4;
                int i0, i1, i2, i3;
                if (use_lds) {
                    i0 = EIdx[eb];
                    i1 = (eb + 1 < e1) ? EIdx[eb + 1] : N_NODES;
                    i2 = (eb + 2 < e1) ? EIdx[eb + 2] : N_NODES;
                    i3 = (eb + 3 < e1) ? EIdx[eb + 3] : N_NODES;
                } else {
                    i0 = esrc[lo + eb];
                    i1 = (eb + 1 < e1) ? esrc[lo + eb + 1] : N_NODES;
                    i2 = (eb + 2 < e1) ? esrc[lo + eb + 2] : N_NODES;
                    i3 = (eb + 3 < e1) ? esrc[lo + eb + 3] : N_NODES;
                }
                size_t s0 = (size_t)i0 * KP, s1 = (size_t)i1 * KP;
                size_t s2 = (size_t)i2 * KP, s3 = (size_t)i3 * KP;
                bfrag a0 = *(const bfrag*)(hcur + s0 + colA);
                bfrag a1 = *(const bfrag*)(hcur + s1 + colA);
                bfrag a2 = *(const bfrag*)(hcur + s2 + colA);
                bfrag a3 = *(const bfrag*)(hcur + s3 + colA);
                if (sumB) {
                    bfrag b0 = *(const bfrag*)(hcur + s0 + colB);
                    bfrag b1 = *(const bfrag*)(hcur + s1 + colB);
                    bfrag b2 = *(const bfrag*)(hcur + s2 + colB);
                    bfrag b3 = *(const bfrag*)(hcur + s3 + colB);
                    #pragma unroll
                    for (int q = 0; q < 8; ++q)
                        b[q] += (bf2f(b0[q]) + bf2f(b1[q])) + (bf2f(b2[q]) + bf2f(b3[q]));
                }
                #pragma unroll
                for (int q = 0; q < 8; ++q)
                    a[q] += (bf2f(a0[q]) + bf2f(a1[q])) + (bf2f(a2[q]) + bf2f(a3[q]));
            }
        }
        // pack + store (unconditional: rows >= N_NODES store zeros -> clean pad rows)
        __hip_bfloat16 oa[8], ob[8];
        #pragma unroll
        for (int q = 0; q < 8; ++q) {
            oa[q] = __float2bfloat16(a[q]);
            ob[q] = __float2bfloat16(b[q]);
        }
        __hip_bfloat16* arow = Ascr + (size_t)n * KP;
        *(ushort4*)(arow + colA)     = *(const ushort4*)&oa[0];
        *(ushort4*)(arow + colA + 4) = *(const ushort4*)&oa[4];
        if (ck < 12) {   // cols 128..223; cols 200..223 get zeros (b stayed 0)
            *(ushort4*)(arow + colB)     = *(const ushort4*)&ob[0];
            *(ushort4*)(arow + colB + 4) = *(const ushort4*)&ob[4];
        }
    }
}

// ---------------- MFMA GRU (+ pool on last step) — NO LDS STAGING ----------------
// v7: v6's null result (grid 512 vs 782: identical 126.5us) proved the 26-round
// barrier'd DMA pipeline was the bottleneck, not residency: each round's
// vmcnt(0)+s_barrier drain cost ~4.8us vs ~0.2us of compute. g_Wall is stored in
// EXACT fragment order, so bv fragments load DIRECTLY from global (perfectly
// coalesced 16B/lane; weights 2MB = L2-resident; L1 absorbs the 4-waves-same-bytes
// redundancy). All 26 barriers, the LDS double buffer, and every global_load_lds
// are deleted. LDS drops to pmax (832B). Waves run as free load->MFMA streams.
__global__ __launch_bounds__(256, 2) void gemm_gru(const __hip_bfloat16* __restrict__ hcur,
                                                   const __hip_bfloat16* __restrict__ Ascr,
                                                   __hip_bfloat16* __restrict__ hnext,
                                                   unsigned int* __restrict__ pooled,
                                                   int step) {
    __shared__ unsigned int pmax[DP];                   // 832 B
    int tid = threadIdx.x;
    int lane = tid & 63, wave = tid >> 6;
    int mrow = lane & 15, kq = lane >> 4;
    int jcol = lane & 15;
    int rowq = (lane >> 4) * 4;
    bool dopool = (step == NUM_STEPS - 1);

    if (dopool) {
        for (int c = tid; c < DP; c += 256) pmax[c] = 0u;
        __syncthreads();     // pmax init visible before any atomicMax below
    }

    const short* Wstep = g_Wall + (size_t)step * 13 * (2 * HALF_SHORTS);
    int wbase = blockIdx.x * 128 + wave * 32;

    // ---- A fragments from Ascr (direct, fragment-layout-contiguous) ----
    bfrag av[2][7], hv[2][7];
    #pragma unroll
    for (int p = 0; p < 2; ++p) {
        const __hip_bfloat16* arow = Ascr + (size_t)(wbase + p * 16 + mrow) * KP;
        #pragma unroll
        for (int t = 0; t < 7; ++t)
            av[p][t] = *(const bfrag*)(arow + t * 32 + kq * 8);
    }
    // ---- H fragments (resident; cols 200..223 are zero by construction) ----
    const __hip_bfloat16* hrow0 = hcur + (size_t)(wbase + mrow) * KP;
    const __hip_bfloat16* hrow1 = hrow0 + (size_t)16 * KP;
    #pragma unroll
    for (int t = 0; t < 7; ++t) {
        hv[0][t] = *(const bfrag*)(hrow0 + t * 32 + kq * 8);
        hv[1][t] = *(const bfrag*)(hrow1 + t * 32 + kq * 8);
    }

    // acc[0]=r (gi+gh), acc[1]=z (gi+gh), acc[2]=i_n, acc[3]=h_n
    facc acc[4][2];
    unsigned short hold_u[2][4];

    for (int jt = 0; jt < 13; ++jt) {
        int j = jt * 16 + jcol;
        const short* Bgi = Wstep + (size_t)(2 * jt) * HALF_SHORTS;      // gates r,z,n (gi)
        const short* Bgh = Bgi + HALF_SHORTS;                           // gates r,z,n (gh)

        // preload old-h for this jt's epilogue (latency hides under the MFMA stream)
        #pragma unroll
        for (int mf = 0; mf < 2; ++mf)
            #pragma unroll
            for (int r = 0; r < 4; ++r)
                hold_u[mf][r] = *(const unsigned short*)
                    (hcur + (size_t)(wbase + mf * 16 + rowq + r) * KP + j);
        #pragma unroll
        for (int g = 0; g < 4; ++g)
            #pragma unroll
            for (int mf = 0; mf < 2; ++mf) acc[g][mf] = (facc)(0.0f);

        // gi gates (r,z,n_i) consume av -> acc 0,1,2
        #pragma unroll
        for (int t = 0; t < 7; ++t) {
            bfrag bv[3];
            #pragma unroll
            for (int g = 0; g < 3; ++g) bv[g] = bv_load(Bgi, g, t, lane);
            #pragma unroll
            for (int g = 0; g < 3; ++g)
                #pragma unroll
                for (int mf = 0; mf < 2; ++mf)
                    acc[g][mf] = __builtin_amdgcn_mfma_f32_16x16x32_bf16(av[mf][t], bv[g], acc[g][mf], 0, 0, 0);
        }
        // gh gates (r,z,n_h) consume hv -> acc 0,1 (merged) and 3
        #pragma unroll
        for (int t = 0; t < 7; ++t) {
            bfrag bv[3];
            #pragma unroll
            for (int g = 0; g < 3; ++g) bv[g] = bv_load(Bgh, g, t, lane);
            #pragma unroll
            for (int mf = 0; mf < 2; ++mf) {
                acc[0][mf] = __builtin_amdgcn_mfma_f32_16x16x32_bf16(hv[mf][t], bv[0], acc[0][mf], 0, 0, 0);
                acc[1][mf] = __builtin_amdgcn_mfma_f32_16x16x32_bf16(hv[mf][t], bv[1], acc[1][mf], 0, 0, 0);
                acc[3][mf] = __builtin_amdgcn_mfma_f32_16x16x32_bf16(hv[mf][t], bv[2], acc[3][mf], 0, 0, 0);
            }
        }

        // epilogue: C/D layout col=lane&15 (j), row=(lane>>4)*4+reg (m)
        float tmax = 0.0f;
        if (j < D) {
            float bir = g_bias[j],          biz = g_bias[DP + j],     bin = g_bias[2 * DP + j];
            float bhr = g_bias[3 * DP + j], bhz = g_bias[4 * DP + j], bhn = g_bias[5 * DP + j];
            #pragma unroll
            for (int mf = 0; mf < 2; ++mf) {
                int m0 = wbase + mf * 16 + rowq;
                #pragma unroll
                for (int r = 0; r < 4; ++r) {
                    int m = m0 + r;
                    if (m < N_NODES) {
                        float hold = bf2f((short)hold_u[mf][r]);
                        float rr = fast_sigmoid(acc[0][mf][r] + bir + bhr);
                        float zz = fast_sigmoid(acc[1][mf][r] + biz + bhz);
                        float nn = fast_tanh(acc[2][mf][r] + bin + rr * (acc[3][mf][r] + bhn));
                        float hv2 = (1.0f - zz) * nn + zz * hold;
                        hnext[(size_t)m * KP + j] = __float2bfloat16(hv2);
                        if (hv2 > tmax) tmax = hv2;
                    }
                }
            }
            if (dopool) atomicMax(&pmax[j], __float_as_uint(tmax));
        }
    }

    if (dopool) {
        __syncthreads();
        for (int c = tid; c < D; c += 256) atomicMax(&pooled[c], pmax[c]);
    }
}

// ---------------- logits + softmax ----------------
__global__ void head_kernel(const unsigned int* __restrict__ pooled,
                            const float* __restrict__ cls_w,
                            const float* __restrict__ cls_b,
                            float* __restrict__ out) {
    if (threadIdx.x == 0) {
        float l0 = cls_b[0], l1 = cls_b[1];
        for (int d = 0; d < D; ++d) {
            float p = __uint_as_float(pooled[d]);
            l0 += p * cls_w[d];
            l1 += p * cls_w[D + d];
        }
        float mx = l0 > l1 ? l0 : l1;
        float e0 = expf(l0 - mx), e1 = expf(l1 - mx);
        out[0] = e0 / (e0 + e1);
        out[1] = e1 / (e0 + e1);
    }
}

extern "C" void kernel_launch(void* const* d_in, const int* in_sizes, int n_in,
                              void* d_out, int out_size, void* d_ws, size_t ws_size,
                              hipStream_t stream) {
    const float* x     = (const float*)d_in[0];
    const float* W     = (const float*)d_in[1];
    const float* w_ih  = (const float*)d_in[2];
    const float* w_hh  = (const float*)d_in[3];
    const float* b_ih  = (const float*)d_in[4];
    const float* b_hh  = (const float*)d_in[5];
    const float* cls_w = (const float*)d_in[6];
    const float* cls_b = (const float*)d_in[7];
    const int*   ei    = (const int*)d_in[8];
    const int* src = ei;
    const int* dst = ei + N_EDGES;

    const size_t ROWB = (size_t)N_PAD * KP;     // bf16 elements per buffer
    __hip_bfloat16* hA   = (__hip_bfloat16*)d_ws;
    __hip_bfloat16* hB   = hA + ROWB;
    __hip_bfloat16* Ascr = hB + ROWB;           // aggregated-message scratch (3rd buffer)
    int* cnt    = (int*)(Ascr + ROWB);
    int* incl   = cnt + N_NODES;
    int* bsum   = incl + N_NODES;
    int* off    = bsum + 128;
    int* cursor = off + N_NODES + 1;
    int* esrc   = cursor + N_NODES;
    unsigned int* pooled = (unsigned int*)(esrc + N_EDGES);

    // CSR build (once per call; edges are step-invariant)
    hipMemsetAsync(cnt, 0, N_NODES * sizeof(int), stream);
    count_kernel<<<(N_EDGES + 255) / 256, 256, 0, stream>>>(dst, cnt);
    scan1<<<NB_SCAN, SCAN_B, 0, stream>>>(cnt, incl, bsum);
    scan3<<<(N_NODES + 255) / 256, 256, 0, stream>>>(cnt, incl, bsum, off, cursor);
    fill_kernel<<<(N_EDGES + 255) / 256, 256, 0, stream>>>(src, dst, cursor, esrc);

    // weight prep (one kernel: fragment permute + Wc fold + bias)
    wconv_kernel<<<WCONV_BLOCKS + 5, 256, 0, stream>>>(W, w_ih, w_hh, b_ih, b_hh);

    pad_kernel<<<(int)(ROWB / 256), 256, 0, stream>>>(x, hA);
    // hB fully zeroed once: (a) gather's clamped batches read zero-row N_NODES on
    // odd steps, (b) cols 200..223 stay zero forever -> hv t=6 is a plain load.
    hipMemsetAsync(hB, 0, ROWB * sizeof(__hip_bfloat16), stream);
    hipMemsetAsync(pooled, 0, D * sizeof(unsigned int), stream);

    __hip_bfloat16* hcur = hA;
    __hip_bfloat16* hnext = hB;
    for (int s = 0; s < NUM_STEPS; ++s) {
        gather_kernel<<<N_PAD / 32, 256, 0, stream>>>(hcur, Ascr, off, esrc);
        gemm_gru<<<N_PAD / 128, 256, 0, stream>>>(hcur, Ascr, hnext, pooled, s);
        __hip_bfloat16* t = hcur; hcur = hnext; hnext = t;
    }
    head_kernel<<<1, 64, 0, stream>>>(pooled, cls_w, cls_b, (float*)d_out);
}

// Round 8
// 851.712 us; speedup vs baseline: 1.4892x; 1.4892x over previous
//
#include <hip/hip_runtime.h>
#include <hip/hip_bf16.h>
#include <math.h>

#define N_NODES 100000
#define N_PAD   100096   // multiple of 256
#define N_EDGES 400000
#define IN_DIM  100
#define D       200
#define DP      208      // j padded to 13*16
#define KP      224      // k padded to 7*32
#define NUM_STEPS 4

// Truncated staged half-tile: 3 gates x (6 full t-blocks * 512 + t6 kq0 slice 128) = 9600
// shorts + 128 pad shorts so staging is whole-64-lane-group granular (1216 x 16B chunks).
#define HALF_SHORTS   9728
#define STAGE_GROUPS  19           // 9728*2B / (64 lanes * 16B)
#define GCAP          512          // per-wave edge-index LDS capacity in gather kernel
#define WCHUNKS_PER_SJT 2432       // 2 halves * 1216 chunks
#define WCONV_BLOCKS  494          // 4*13*2432 / 256

typedef __attribute__((ext_vector_type(8))) short bfrag;   // 8 bf16 (4 VGPRs)
typedef __attribute__((ext_vector_type(4))) float facc;    // 4 fp32

// weights, per-(step,jt) contiguous TRUNCATED tile: [s][jt][half2][gg3][t-compact]
__device__ short g_Wall[NUM_STEPS * 13 * 2 * HALF_SHORTS];
__device__ float g_bias[6 * DP];

__device__ __forceinline__ float fast_sigmoid(float x) {
    return __builtin_amdgcn_rcpf(1.0f + __expf(-x));
}
__device__ __forceinline__ float fast_tanh(float x) {
    return 2.0f * __builtin_amdgcn_rcpf(1.0f + __expf(-2.0f * x)) - 1.0f;
}
__device__ __forceinline__ float bf2f(short u) {
    unsigned int x = ((unsigned int)(unsigned short)u) << 16;
    return __uint_as_float(x);
}

// ---------------- weight permute + Wc-fold + bias, all in one kernel ----------------
// Compact layout per (s,jt,half): gate gg in 0..2 at gg*3200 shorts:
//   t<6: gg*3200 + t*512 + lane*8      (lane 0..63)
//   t=6: gg*3200 + 3072 + l*8          (l 0..15, kq=0 slice only; k>=200 is dead: A-side zero)
// chunks 1200..1215 of each half are zero padding.
__global__ __launch_bounds__(256) void wconv_kernel(const float* __restrict__ W,
                                                    const float* __restrict__ w_ih,
                                                    const float* __restrict__ w_hh,
                                                    const float* __restrict__ b_ih,
                                                    const float* __restrict__ b_hh) {
    if (blockIdx.x >= WCONV_BLOCKS) {
        int idx = (blockIdx.x - WCONV_BLOCKS) * 256 + threadIdx.x;
        if (idx < 6 * DP) {
            int g = idx / DP, j = idx % DP;
            float v = 0.0f;
            if (j < D) v = (g < 3) ? b_ih[g * 200 + j] : b_hh[(g - 3) * 200 + j];
            g_bias[idx] = v;
        }
        return;
    }
    int idx = blockIdx.x * 256 + threadIdx.x;   // chunk id < 4*13*2432 = 126464
    short* out = g_Wall + (size_t)idx * 8;
    int s    = idx / (13 * WCHUNKS_PER_SJT);
    int rem  = idx % (13 * WCHUNKS_PER_SJT);
    int jt   = rem / WCHUNKS_PER_SJT;
    int r2   = rem % WCHUNKS_PER_SJT;
    int half = r2 / 1216;
    int c    = r2 % 1216;
    if (c >= 1200) {                       // pad chunks: store zeros
        #pragma unroll
        for (int i = 0; i < 8; ++i) out[i] = 0;
        return;
    }
    int gg = c / 400, cc = c % 400;
    int t  = (cc < 384) ? (cc >> 6) : 6;
    int l  = (cc < 384) ? (cc & 63) : (cc - 384);
    int g  = half * 3 + gg;
    int j  = jt * 16 + (l & 15);
    int k0 = t * 32 + (l >> 4) * 8;
    float vals[8];
    if (g < 3) {
        // fold: vals[i] = dot(w_ih[g*200+j], W[s][k0+i])
        const float* wr = (j < D) ? &w_ih[(size_t)(g * 200 + j) * D] : nullptr;
        #pragma unroll
        for (int i = 0; i < 8; ++i) vals[i] = 0.0f;
        if (wr) {
            #pragma unroll
            for (int i = 0; i < 8; ++i) {
                int k = k0 + i;
                if (k < D) {
                    const float* Wr = &W[(size_t)s * D * D + (size_t)k * D];
                    float acc = 0.0f;
                    #pragma unroll 4
                    for (int tt = 0; tt < D; ++tt) acc += wr[tt] * Wr[tt];
                    vals[i] = acc;
                }
            }
        }
    } else {
        #pragma unroll
        for (int i = 0; i < 8; ++i) {
            int k = k0 + i;
            vals[i] = (j < D && k < D) ? w_hh[((size_t)(g - 3) * 200 + j) * D + k] : 0.0f;
        }
    }
    #pragma unroll
    for (int i = 0; i < 8; ++i) {
        __hip_bfloat16 b = __float2bfloat16(vals[i]);
        out[i] = *reinterpret_cast<short*>(&b);
    }
}

// ---------------- pad: h[:, :100] = bf16(x), rest 0 ----------------
__global__ void pad_kernel(const float* __restrict__ x, __hip_bfloat16* __restrict__ h) {
    int idx = blockIdx.x * 256 + threadIdx.x;   // N_PAD*KP exact multiple of 256
    int n = idx / KP, c = idx % KP;
    float v = (n < N_NODES && c < IN_DIM) ? x[n * IN_DIM + c] : 0.0f;
    h[idx] = __float2bfloat16(v);
}

// ---------------- CSR build ----------------
__global__ void count_kernel(const int* __restrict__ dst, int* __restrict__ cnt) {
    int e = blockIdx.x * blockDim.x + threadIdx.x;
    if (e < N_EDGES) atomicAdd(&cnt[dst[e]], 1);
}

#define SCAN_B 1024
#define NB_SCAN ((N_NODES + SCAN_B - 1) / SCAN_B)   // 98
__global__ __launch_bounds__(SCAN_B) void scan1(const int* __restrict__ cnt,
                                                int* __restrict__ incl, int* __restrict__ bsum) {
    __shared__ int ws[16];
    int i = blockIdx.x * SCAN_B + threadIdx.x;
    int lane = threadIdx.x & 63, wid = threadIdx.x >> 6;
    int v = (i < N_NODES) ? cnt[i] : 0;
    int s = v;
    #pragma unroll
    for (int o = 1; o < 64; o <<= 1) {
        int t = __shfl_up(s, o, 64);
        if (lane >= o) s += t;
    }
    if (lane == 63) ws[wid] = s;
    __syncthreads();
    if (wid == 0) {
        int t = (lane < 16) ? ws[lane] : 0;
        #pragma unroll
        for (int o = 1; o < 16; o <<= 1) {
            int u = __shfl_up(t, o, 64);
            if (lane >= o) t += u;
        }
        if (lane < 16) ws[lane] = t;
    }
    __syncthreads();
    if (wid > 0) s += ws[wid - 1];
    if (i < N_NODES) incl[i] = s;
    if (threadIdx.x == SCAN_B - 1) bsum[blockIdx.x] = s;
}
__global__ void scan3(const int* __restrict__ cnt, const int* __restrict__ incl,
                      const int* __restrict__ bsum, int* __restrict__ off,
                      int* __restrict__ cursor) {
    __shared__ int sh[128];
    if (threadIdx.x < 128) sh[threadIdx.x] = (threadIdx.x < NB_SCAN) ? bsum[threadIdx.x] : 0;
    __syncthreads();
    for (int o = 1; o < 128; o <<= 1) {
        int t = (threadIdx.x >= o && threadIdx.x < 128) ? sh[threadIdx.x - o] : 0;
        __syncthreads();
        if (threadIdx.x < 128) sh[threadIdx.x] += t;
        __syncthreads();
    }
    int i = blockIdx.x * blockDim.x + threadIdx.x;
    if (i < N_NODES) {
        int b = i / SCAN_B;
        int pre = b ? sh[b - 1] : 0;
        int v = incl[i] - cnt[i] + pre;
        off[i] = v; cursor[i] = v;
    }
    if (i == 0) off[N_NODES] = N_EDGES;
}
__global__ void fill_kernel(const int* __restrict__ src, const int* __restrict__ dst,
                            int* __restrict__ cursor, int* __restrict__ esrc) {
    int e = blockIdx.x * blockDim.x + threadIdx.x;
    if (e < N_EDGES) {
        int pos = atomicAdd(&cursor[dst[e]], 1);
        esrc[pos] = src[e];
    }
}

// ---------------- async stage: one TRUNCATED half (19456 B) global -> LDS ----------------
__device__ __forceinline__ void stage_half(const short* __restrict__ gsrc,
                                           short* lds_dst, int wave, int lane) {
    #pragma unroll
    for (int g = wave; g < STAGE_GROUPS; g += 4) {
        __builtin_amdgcn_global_load_lds(
            (const __attribute__((address_space(1))) void*)(gsrc + g * 512 + lane * 8),
            (__attribute__((address_space(3))) void*)(lds_dst + g * 512),
            16, 0, 0);
    }
}

// B-fragment read from truncated staged half. t is compile-time (unrolled loops).
// t=6, lanes kq>=1: k>=200 where A-side is structurally zero -> supply zeros (NaN-safe).
__device__ __forceinline__ bfrag bv_load(const short* Bcur, int g, int t, int lane) {
    if (t < 6) return *(const bfrag*)(Bcur + g * 3200 + t * 512 + lane * 8);
    bfrag z;
    #pragma unroll
    for (int i = 0; i < 8; ++i) z[i] = 0;
    if (lane < 16) z = *(const bfrag*)(Bcur + g * 3200 + 3072 + lane * 8);
    return z;
}

// ---------------- gather/aggregate kernel ----------------
// Latency/occupancy-bound (v3/v4 evidence: BW scales with resident waves). 8 rows
// per wave, grid 3128, GCAP 512 -> 8 KB LDS/block; streams through the 32-wave/CU cap.
__global__ __launch_bounds__(256) void gather_kernel(const __hip_bfloat16* __restrict__ hcur,
                                                     __hip_bfloat16* __restrict__ Ascr,
                                                     const int* __restrict__ off,
                                                     const int* __restrict__ esrc) {
    __shared__ int EIdxAll[4 * GCAP];   // 8192 B
    int tid = threadIdx.x;
    int lane = tid & 63, wave = tid >> 6;
    int wbase = blockIdx.x * 32 + wave * 8;
    int* EIdx = EIdxAll + wave * GCAP;

    // prefetch this wave's contiguous esrc slice (CSR rows are contiguous)
    int nlo = wbase < N_NODES ? wbase : N_NODES;
    int nhi = (wbase + 8) < N_NODES ? (wbase + 8) : N_NODES;
    int lo = off[nlo];
    int cntw = off[nhi] - lo;
    bool use_lds = (cntw <= GCAP);
    if (use_lds)
        for (int i = lane; i < cntw; i += 64) EIdx[i] = esrc[lo + i];

    int r4 = lane >> 4;              // row-in-flight 0..3
    int ck = lane & 15;              // 16B chunk id (this lane also covers ck+16)
    int colA = ck * 8;
    int colB = colA + 128;           // (ck+16)*8
    bool sumB = (ck < 9);            // chunks 16..24 carry data (cols < 200)
    #pragma unroll
    for (int it = 0; it < 2; ++it) {
        int rr = it * 4 + r4;
        int n = wbase + rr;
        float a[8] = {0, 0, 0, 0, 0, 0, 0, 0};
        float b[8] = {0, 0, 0, 0, 0, 0, 0, 0};
        if (n < N_NODES) {
            int e0 = off[n] - lo, e1 = off[n + 1] - lo;
            int nb = (e1 - e0 + 3) >> 2;
            for (int bq = 0; bq < nb; ++bq) {
                int eb = e0 + bq * 4;
                int i0, i1, i2, i3;
                if (use_lds) {
                    i0 = EIdx[eb];
                    i1 = (eb + 1 < e1) ? EIdx[eb + 1] : N_NODES;
                    i2 = (eb + 2 < e1) ? EIdx[eb + 2] : N_NODES;
                    i3 = (eb + 3 < e1) ? EIdx[eb + 3] : N_NODES;
                } else {
                    i0 = esrc[lo + eb];
                    i1 = (eb + 1 < e1) ? esrc[lo + eb + 1] : N_NODES;
                    i2 = (eb + 2 < e1) ? esrc[lo + eb + 2] : N_NODES;
                    i3 = (eb + 3 < e1) ? esrc[lo + eb + 3] : N_NODES;
                }
                size_t s0 = (size_t)i0 * KP, s1 = (size_t)i1 * KP;
                size_t s2 = (size_t)i2 * KP, s3 = (size_t)i3 * KP;
                bfrag a0 = *(const bfrag*)(hcur + s0 + colA);
                bfrag a1 = *(const bfrag*)(hcur + s1 + colA);
                bfrag a2 = *(const bfrag*)(hcur + s2 + colA);
                bfrag a3 = *(const bfrag*)(hcur + s3 + colA);
                if (sumB) {
                    bfrag b0 = *(const bfrag*)(hcur + s0 + colB);
                    bfrag b1 = *(const bfrag*)(hcur + s1 + colB);
                    bfrag b2 = *(const bfrag*)(hcur + s2 + colB);
                    bfrag b3 = *(const bfrag*)(hcur + s3 + colB);
                    #pragma unroll
                    for (int q = 0; q < 8; ++q)
                        b[q] += (bf2f(b0[q]) + bf2f(b1[q])) + (bf2f(b2[q]) + bf2f(b3[q]));
                }
                #pragma unroll
                for (int q = 0; q < 8; ++q)
                    a[q] += (bf2f(a0[q]) + bf2f(a1[q])) + (bf2f(a2[q]) + bf2f(a3[q]));
            }
        }
        // pack + store (unconditional: rows >= N_NODES store zeros -> clean pad rows)
        __hip_bfloat16 oa[8], ob[8];
        #pragma unroll
        for (int q = 0; q < 8; ++q) {
            oa[q] = __float2bfloat16(a[q]);
            ob[q] = __float2bfloat16(b[q]);
        }
        __hip_bfloat16* arow = Ascr + (size_t)n * KP;
        *(ushort4*)(arow + colA)     = *(const ushort4*)&oa[0];
        *(ushort4*)(arow + colA + 4) = *(const ushort4*)&oa[4];
        if (ck < 12) {   // cols 128..223; cols 200..223 get zeros (b stayed 0)
            *(ushort4*)(arow + colB)     = *(const ushort4*)&ob[0];
            *(ushort4*)(arow + colB + 4) = *(const ushort4*)&ob[4];
        }
    }
}

// ---------------- MFMA GRU (+ pool on last step) ----------------
// v8 CONVOY FIX: v5/v6 ran all 782 blocks through the 26 weight half-tiles in
// LOCKSTEP -> at every round, every block's DMA requested the SAME ~300 cache
// lines; per-XCD L2 serialized ~98 same-line requests -> 4.85us/round convoy
// (explains v6's grid-782-vs-512 null and v7's direct-global 226us disaster;
// r0's fused kernel was fast in its gemm section because variable-length gather
// naturally de-phased blocks). The 13 jt column-tiles are fully independent
// (acc resets per jt, epilogue per jt), so block b starts at jt = b%13 and
// wraps: at any instant, blocks spread over the whole 506 KB step-tile (60-way
// line sharing instead of 782-way). Everything else identical to v6.
__global__ __launch_bounds__(256, 2) void gemm_gru(const __hip_bfloat16* __restrict__ hcur,
                                                   const __hip_bfloat16* __restrict__ Ascr,
                                                   __hip_bfloat16* __restrict__ hnext,
                                                   unsigned int* __restrict__ pooled,
                                                   int step) {
    __shared__ __align__(16) short Bs[2][HALF_SHORTS];  // 38912 B, weights only
    __shared__ unsigned int pmax[DP];                   // 832 B
    int tid = threadIdx.x;
    int lane = tid & 63, wave = tid >> 6;
    int mrow = lane & 15, kq = lane >> 4;
    int jcol = lane & 15;
    int rowq = (lane >> 4) * 4;
    bool dopool = (step == NUM_STEPS - 1);

    if (dopool) for (int c = tid; c < DP; c += 256) pmax[c] = 0u;

    const short* Wstep = g_Wall + (size_t)step * 13 * (2 * HALF_SHORTS);
    int wbase = blockIdx.x * 128 + wave * 32;
    int phase = blockIdx.x % 13;            // de-phase: starting jt differs per block

    // half index i (0..25) -> rotated global address
    auto halfptr = [&](int i) {
        int q = phase + (i >> 1); if (q >= 13) q -= 13;
        return Wstep + (size_t)(2 * q + (i & 1)) * HALF_SHORTS;
    };

    stage_half(halfptr(0), &Bs[0][0], wave, lane);   // issue first-half DMA ASAP

    // ---- A fragments from Ascr (direct, fragment-layout-contiguous) ----
    bfrag av[2][7], hv[2][7];
    #pragma unroll
    for (int p = 0; p < 2; ++p) {
        const __hip_bfloat16* arow = Ascr + (size_t)(wbase + p * 16 + mrow) * KP;
        #pragma unroll
        for (int t = 0; t < 7; ++t)
            av[p][t] = *(const bfrag*)(arow + t * 32 + kq * 8);
    }
    // ---- H fragments (resident; cols 200..223 are zero by construction) ----
    const __hip_bfloat16* hrow0 = hcur + (size_t)(wbase + mrow) * KP;
    const __hip_bfloat16* hrow1 = hrow0 + (size_t)16 * KP;
    #pragma unroll
    for (int t = 0; t < 7; ++t) {
        hv[0][t] = *(const bfrag*)(hrow0 + t * 32 + kq * 8);
        hv[1][t] = *(const bfrag*)(hrow1 + t * 32 + kq * 8);
    }

    // acc[0]=r (gi+gh), acc[1]=z (gi+gh), acc[2]=i_n, acc[3]=h_n
    facc acc[4][2];
    unsigned short hold_u[2][4];

    for (int hk = 0; hk < 26; ++hk) {
        __syncthreads();   // h_hk DMA complete; buf[(hk+1)&1] free for restage
        if (hk + 1 < 26)
            stage_half(halfptr(hk + 1), &Bs[(hk + 1) & 1][0], wave, lane);

        int jt = phase + (hk >> 1); if (jt >= 13) jt -= 13;
        int j = jt * 16 + jcol;
        const short* Bcur = &Bs[hk & 1][0];

        if ((hk & 1) == 0) {
            // preload old-h for this jt's epilogue (latency hides under both halves)
            #pragma unroll
            for (int mf = 0; mf < 2; ++mf)
                #pragma unroll
                for (int r = 0; r < 4; ++r)
                    hold_u[mf][r] = *(const unsigned short*)
                        (hcur + (size_t)(wbase + mf * 16 + rowq + r) * KP + j);
            #pragma unroll
            for (int g = 0; g < 4; ++g)
                #pragma unroll
                for (int mf = 0; mf < 2; ++mf) acc[g][mf] = (facc)(0.0f);
            // gi gates (r,z,n_i) consume av -> acc 0,1,2
            #pragma unroll
            for (int t = 0; t < 7; ++t) {
                bfrag bv[3];
                #pragma unroll
                for (int g = 0; g < 3; ++g) bv[g] = bv_load(Bcur, g, t, lane);
                #pragma unroll
                for (int g = 0; g < 3; ++g)
                    #pragma unroll
                    for (int mf = 0; mf < 2; ++mf)
                        acc[g][mf] = __builtin_amdgcn_mfma_f32_16x16x32_bf16(av[mf][t], bv[g], acc[g][mf], 0, 0, 0);
            }
        } else {
            // gh gates (r,z,n_h) consume hv -> acc 0,1 (merged) and 3
            #pragma unroll
            for (int t = 0; t < 7; ++t) {
                bfrag bv[3];
                #pragma unroll
                for (int g = 0; g < 3; ++g) bv[g] = bv_load(Bcur, g, t, lane);
                #pragma unroll
                for (int mf = 0; mf < 2; ++mf) {
                    acc[0][mf] = __builtin_amdgcn_mfma_f32_16x16x32_bf16(hv[mf][t], bv[0], acc[0][mf], 0, 0, 0);
                    acc[1][mf] = __builtin_amdgcn_mfma_f32_16x16x32_bf16(hv[mf][t], bv[1], acc[1][mf], 0, 0, 0);
                    acc[3][mf] = __builtin_amdgcn_mfma_f32_16x16x32_bf16(hv[mf][t], bv[2], acc[3][mf], 0, 0, 0);
                }
            }

            // epilogue: C/D layout col=lane&15 (j), row=(lane>>4)*4+reg (m)
            float tmax = 0.0f;
            if (j < D) {
                float bir = g_bias[j],          biz = g_bias[DP + j],     bin = g_bias[2 * DP + j];
                float bhr = g_bias[3 * DP + j], bhz = g_bias[4 * DP + j], bhn = g_bias[5 * DP + j];
                #pragma unroll
                for (int mf = 0; mf < 2; ++mf) {
                    int m0 = wbase + mf * 16 + rowq;
                    #pragma unroll
                    for (int r = 0; r < 4; ++r) {
                        int m = m0 + r;
                        if (m < N_NODES) {
                            float hold = bf2f((short)hold_u[mf][r]);
                            float rr = fast_sigmoid(acc[0][mf][r] + bir + bhr);
                            float zz = fast_sigmoid(acc[1][mf][r] + biz + bhz);
                            float nn = fast_tanh(acc[2][mf][r] + bin + rr * (acc[3][mf][r] + bhn));
                            float hv2 = (1.0f - zz) * nn + zz * hold;
                            hnext[(size_t)m * KP + j] = __float2bfloat16(hv2);
                            if (hv2 > tmax) tmax = hv2;
                        }
                    }
                }
                if (dopool) atomicMax(&pmax[j], __float_as_uint(tmax));
            }
        }
    }

    if (dopool) {
        __syncthreads();
        for (int c = tid; c < D; c += 256) atomicMax(&pooled[c], pmax[c]);
    }
}

// ---------------- logits + softmax ----------------
__global__ void head_kernel(const unsigned int* __restrict__ pooled,
                            const float* __restrict__ cls_w,
                            const float* __restrict__ cls_b,
                            float* __restrict__ out) {
    if (threadIdx.x == 0) {
        float l0 = cls_b[0], l1 = cls_b[1];
        for (int d = 0; d < D; ++d) {
            float p = __uint_as_float(pooled[d]);
            l0 += p * cls_w[d];
            l1 += p * cls_w[D + d];
        }
        float mx = l0 > l1 ? l0 : l1;
        float e0 = expf(l0 - mx), e1 = expf(l1 - mx);
        out[0] = e0 / (e0 + e1);
        out[1] = e1 / (e0 + e1);
    }
}

extern "C" void kernel_launch(void* const* d_in, const int* in_sizes, int n_in,
                              void* d_out, int out_size, void* d_ws, size_t ws_size,
                              hipStream_t stream) {
    const float* x     = (const float*)d_in[0];
    const float* W     = (const float*)d_in[1];
    const float* w_ih  = (const float*)d_in[2];
    const float* w_hh  = (const float*)d_in[3];
    const float* b_ih  = (const float*)d_in[4];
    const float* b_hh  = (const float*)d_in[5];
    const float* cls_w = (const float*)d_in[6];
    const float* cls_b = (const float*)d_in[7];
    const int*   ei    = (const int*)d_in[8];
    const int* src = ei;
    const int* dst = ei + N_EDGES;

    const size_t ROWB = (size_t)N_PAD * KP;     // bf16 elements per buffer
    __hip_bfloat16* hA   = (__hip_bfloat16*)d_ws;
    __hip_bfloat16* hB   = hA + ROWB;
    __hip_bfloat16* Ascr = hB + ROWB;           // aggregated-message scratch (3rd buffer)
    int* cnt    = (int*)(Ascr + ROWB);
    int* incl   = cnt + N_NODES;
    int* bsum   = incl + N_NODES;
    int* off    = bsum + 128;
    int* cursor = off + N_NODES + 1;
    int* esrc   = cursor + N_NODES;
    unsigned int* pooled = (unsigned int*)(esrc + N_EDGES);

    // CSR build (once per call; edges are step-invariant)
    hipMemsetAsync(cnt, 0, N_NODES * sizeof(int), stream);
    count_kernel<<<(N_EDGES + 255) / 256, 256, 0, stream>>>(dst, cnt);
    scan1<<<NB_SCAN, SCAN_B, 0, stream>>>(cnt, incl, bsum);
    scan3<<<(N_NODES + 255) / 256, 256, 0, stream>>>(cnt, incl, bsum, off, cursor);
    fill_kernel<<<(N_EDGES + 255) / 256, 256, 0, stream>>>(src, dst, cursor, esrc);

    // weight prep (one kernel: fragment permute + Wc fold + bias)
    wconv_kernel<<<WCONV_BLOCKS + 5, 256, 0, stream>>>(W, w_ih, w_hh, b_ih, b_hh);

    pad_kernel<<<(int)(ROWB / 256), 256, 0, stream>>>(x, hA);
    // hB fully zeroed once: (a) gather's clamped batches read zero-row N_NODES on
    // odd steps, (b) cols 200..223 stay zero forever -> hv t=6 is a plain load.
    hipMemsetAsync(hB, 0, ROWB * sizeof(__hip_bfloat16), stream);
    hipMemsetAsync(pooled, 0, D * sizeof(unsigned int), stream);

    __hip_bfloat16* hcur = hA;
    __hip_bfloat16* hnext = hB;
    for (int s = 0; s < NUM_STEPS; ++s) {
        gather_kernel<<<N_PAD / 32, 256, 0, stream>>>(hcur, Ascr, off, esrc);
        gemm_gru<<<N_PAD / 128, 256, 0, stream>>>(hcur, Ascr, hnext, pooled, s);
        __hip_bfloat16* t = hcur; hcur = hnext; hnext = t;
    }
    head_kernel<<<1, 64, 0, stream>>>(pooled, cls_w, cls_b, (float*)d_out);
}

// Round 10
// 832.232 us; speedup vs baseline: 1.5240x; 1.0234x over previous
//
#include <hip/hip_runtime.h>
#include <hip/hip_bf16.h>
#include <math.h>

#define N_NODES 100000
#define N_PAD   100096   // multiple of 256
#define N_EDGES 400000
#define IN_DIM  100
#define D       200
#define DP      208      // j padded to 13*16
#define KP      224      // k padded to 7*32
#define NUM_STEPS 4

// Truncated half-tile: 3 gates x (6 full t-blocks * 512 + t6 kq0 slice 128) = 9600
// shorts + 128 pad shorts (1216 x 16B chunks). A FULL jt tile = gi half + gh half.
#define HALF_SHORTS   9728
#define FULL_SHORTS   (2 * HALF_SHORTS)   // 19456 shorts = 38912 B
#define STAGE_GROUPS_FULL 38              // 19456 shorts / (64 lanes * 8 shorts)
#define GCAP          512          // per-wave edge-index LDS capacity in gather kernel
#define WCHUNKS_PER_SJT 2432       // 2 halves * 1216 chunks
#define WCONV_BLOCKS  494          // 4*13*2432 / 256

typedef __attribute__((ext_vector_type(8))) short bfrag;   // 8 bf16 (4 VGPRs)
typedef __attribute__((ext_vector_type(4))) float facc;    // 4 fp32

// weights, per-(step,jt) contiguous TRUNCATED tile: [s][jt][half2][gg3][t-compact]
__device__ short g_Wall[NUM_STEPS * 13 * 2 * HALF_SHORTS];
__device__ float g_bias[6 * DP];

__device__ __forceinline__ float fast_sigmoid(float x) {
    return __builtin_amdgcn_rcpf(1.0f + __expf(-x));
}
__device__ __forceinline__ float fast_tanh(float x) {
    return 2.0f * __builtin_amdgcn_rcpf(1.0f + __expf(-2.0f * x)) - 1.0f;
}
__device__ __forceinline__ float bf2f(short u) {
    unsigned int x = ((unsigned int)(unsigned short)u) << 16;
    return __uint_as_float(x);
}

// ---------------- weight permute + Wc-fold + bias, all in one kernel ----------------
// Compact layout per (s,jt,half): gate gg in 0..2 at gg*3200 shorts:
//   t<6: gg*3200 + t*512 + lane*8      (lane 0..63)
//   t=6: gg*3200 + 3072 + l*8          (l 0..15, kq=0 slice only; k>=200 is dead: A-side zero)
// chunks 1200..1215 of each half are zero padding.
__global__ __launch_bounds__(256) void wconv_kernel(const float* __restrict__ W,
                                                    const float* __restrict__ w_ih,
                                                    const float* __restrict__ w_hh,
                                                    const float* __restrict__ b_ih,
                                                    const float* __restrict__ b_hh) {
    if (blockIdx.x >= WCONV_BLOCKS) {
        int idx = (blockIdx.x - WCONV_BLOCKS) * 256 + threadIdx.x;
        if (idx < 6 * DP) {
            int g = idx / DP, j = idx % DP;
            float v = 0.0f;
            if (j < D) v = (g < 3) ? b_ih[g * 200 + j] : b_hh[(g - 3) * 200 + j];
            g_bias[idx] = v;
        }
        return;
    }
    int idx = blockIdx.x * 256 + threadIdx.x;   // chunk id < 4*13*2432 = 126464
    short* out = g_Wall + (size_t)idx * 8;
    int s    = idx / (13 * WCHUNKS_PER_SJT);
    int rem  = idx % (13 * WCHUNKS_PER_SJT);
    int jt   = rem / WCHUNKS_PER_SJT;
    int r2   = rem % WCHUNKS_PER_SJT;
    int half = r2 / 1216;
    int c    = r2 % 1216;
    if (c >= 1200) {                       // pad chunks: store zeros
        #pragma unroll
        for (int i = 0; i < 8; ++i) out[i] = 0;
        return;
    }
    int gg = c / 400, cc = c % 400;
    int t  = (cc < 384) ? (cc >> 6) : 6;
    int l  = (cc < 384) ? (cc & 63) : (cc - 384);
    int g  = half * 3 + gg;
    int j  = jt * 16 + (l & 15);
    int k0 = t * 32 + (l >> 4) * 8;
    float vals[8];
    if (g < 3) {
        // fold: vals[i] = dot(w_ih[g*200+j], W[s][k0+i])
        const float* wr = (j < D) ? &w_ih[(size_t)(g * 200 + j) * D] : nullptr;
        #pragma unroll
        for (int i = 0; i < 8; ++i) vals[i] = 0.0f;
        if (wr) {
            #pragma unroll
            for (int i = 0; i < 8; ++i) {
                int k = k0 + i;
                if (k < D) {
                    const float* Wr = &W[(size_t)s * D * D + (size_t)k * D];
                    float acc = 0.0f;
                    #pragma unroll 4
                    for (int tt = 0; tt < D; ++tt) acc += wr[tt] * Wr[tt];
                    vals[i] = acc;
                }
            }
        }
    } else {
        #pragma unroll
        for (int i = 0; i < 8; ++i) {
            int k = k0 + i;
            vals[i] = (j < D && k < D) ? w_hh[((size_t)(g - 3) * 200 + j) * D + k] : 0.0f;
        }
    }
    #pragma unroll
    for (int i = 0; i < 8; ++i) {
        __hip_bfloat16 b = __float2bfloat16(vals[i]);
        out[i] = *reinterpret_cast<short*>(&b);
    }
}

// ---------------- pad: h[:, :100] = bf16(x), rest 0 ----------------
__global__ void pad_kernel(const float* __restrict__ x, __hip_bfloat16* __restrict__ h) {
    int idx = blockIdx.x * 256 + threadIdx.x;   // N_PAD*KP exact multiple of 256
    int n = idx / KP, c = idx % KP;
    float v = (n < N_NODES && c < IN_DIM) ? x[n * IN_DIM + c] : 0.0f;
    h[idx] = __float2bfloat16(v);
}

// ---------------- CSR build ----------------
__global__ void count_kernel(const int* __restrict__ dst, int* __restrict__ cnt) {
    int e = blockIdx.x * blockDim.x + threadIdx.x;
    if (e < N_EDGES) atomicAdd(&cnt[dst[e]], 1);
}

#define SCAN_B 1024
#define NB_SCAN ((N_NODES + SCAN_B - 1) / SCAN_B)   // 98
__global__ __launch_bounds__(SCAN_B) void scan1(const int* __restrict__ cnt,
                                                int* __restrict__ incl, int* __restrict__ bsum) {
    __shared__ int ws[16];
    int i = blockIdx.x * SCAN_B + threadIdx.x;
    int lane = threadIdx.x & 63, wid = threadIdx.x >> 6;
    int v = (i < N_NODES) ? cnt[i] : 0;
    int s = v;
    #pragma unroll
    for (int o = 1; o < 64; o <<= 1) {
        int t = __shfl_up(s, o, 64);
        if (lane >= o) s += t;
    }
    if (lane == 63) ws[wid] = s;
    __syncthreads();
    if (wid == 0) {
        int t = (lane < 16) ? ws[lane] : 0;
        #pragma unroll
        for (int o = 1; o < 16; o <<= 1) {
            int u = __shfl_up(t, o, 64);
            if (lane >= o) t += u;
        }
        if (lane < 16) ws[lane] = t;
    }
    __syncthreads();
    if (wid > 0) s += ws[wid - 1];
    if (i < N_NODES) incl[i] = s;
    if (threadIdx.x == SCAN_B - 1) bsum[blockIdx.x] = s;
}
__global__ void scan3(const int* __restrict__ cnt, const int* __restrict__ incl,
                      const int* __restrict__ bsum, int* __restrict__ off,
                      int* __restrict__ cursor) {
    __shared__ int sh[128];
    if (threadIdx.x < 128) sh[threadIdx.x] = (threadIdx.x < NB_SCAN) ? bsum[threadIdx.x] : 0;
    __syncthreads();
    for (int o = 1; o < 128; o <<= 1) {
        int t = (threadIdx.x >= o && threadIdx.x < 128) ? sh[threadIdx.x - o] : 0;
        __syncthreads();
        if (threadIdx.x < 128) sh[threadIdx.x] += t;
        __syncthreads();
    }
    int i = blockIdx.x * blockDim.x + threadIdx.x;
    if (i < N_NODES) {
        int b = i / SCAN_B;
        int pre = b ? sh[b - 1] : 0;
        int v = incl[i] - cnt[i] + pre;
        off[i] = v; cursor[i] = v;
    }
    if (i == 0) off[N_NODES] = N_EDGES;
}
__global__ void fill_kernel(const int* __restrict__ src, const int* __restrict__ dst,
                            int* __restrict__ cursor, int* __restrict__ esrc) {
    int e = blockIdx.x * blockDim.x + threadIdx.x;
    if (e < N_EDGES) {
        int pos = atomicAdd(&cursor[dst[e]], 1);
        esrc[pos] = src[e];
    }
}

// ---------------- async stage: one FULL jt tile (38912 B) global -> LDS ----------------
__device__ __forceinline__ void stage_full(const short* __restrict__ gsrc,
                                           short* lds_dst, int wave, int lane) {
    #pragma unroll
    for (int g = wave; g < STAGE_GROUPS_FULL; g += 4) {
        __builtin_amdgcn_global_load_lds(
            (const __attribute__((address_space(1))) void*)(gsrc + g * 512 + lane * 8),
            (__attribute__((address_space(3))) void*)(lds_dst + g * 512),
            16, 0, 0);
    }
}

// B-fragment read from a truncated staged half (base = gi half or gh half).
// t is compile-time (unrolled loops). t=6, lanes kq>=1: k>=200 where A-side is
// structurally zero -> supply zeros (NaN-safe).
__device__ __forceinline__ bfrag bv_load(const short* base, int g, int t, int lane) {
    if (t < 6) return *(const bfrag*)(base + g * 3200 + t * 512 + lane * 8);
    bfrag z;
    #pragma unroll
    for (int i = 0; i < 8; ++i) z[i] = 0;
    if (lane < 16) z = *(const bfrag*)(base + g * 3200 + 3072 + lane * 8);
    return z;
}

// ---------------- gather/aggregate kernel ----------------
// Latency/occupancy-bound (v3/v4 evidence: BW scales with resident waves). 8 rows
// per wave, grid 3128, GCAP 512 -> 8 KB LDS/block; streams through the 32-wave/CU cap.
__global__ __launch_bounds__(256) void gather_kernel(const __hip_bfloat16* __restrict__ hcur,
                                                     __hip_bfloat16* __restrict__ Ascr,
                                                     const int* __restrict__ off,
                                                     const int* __restrict__ esrc) {
    __shared__ int EIdxAll[4 * GCAP];   // 8192 B
    int tid = threadIdx.x;
    int lane = tid & 63, wave = tid >> 6;
    int wbase = blockIdx.x * 32 + wave * 8;
    int* EIdx = EIdxAll + wave * GCAP;

    // prefetch this wave's contiguous esrc slice (CSR rows are contiguous)
    int nlo = wbase < N_NODES ? wbase : N_NODES;
    int nhi = (wbase + 8) < N_NODES ? (wbase + 8) : N_NODES;
    int lo = off[nlo];
    int cntw = off[nhi] - lo;
    bool use_lds = (cntw <= GCAP);
    if (use_lds)
        for (int i = lane; i < cntw; i += 64) EIdx[i] = esrc[lo + i];

    int r4 = lane >> 4;              // row-in-flight 0..3
    int ck = lane & 15;              // 16B chunk id (this lane also covers ck+16)
    int colA = ck * 8;
    int colB = colA + 128;           // (ck+16)*8
    bool sumB = (ck < 9);            // chunks 16..24 carry data (cols < 200)
    #pragma unroll
    for (int it = 0; it < 2; ++it) {
        int rr = it * 4 + r4;
        int n = wbase + rr;
        float a[8] = {0, 0, 0, 0, 0, 0, 0, 0};
        float b[8] = {0, 0, 0, 0, 0, 0, 0, 0};
        if (n < N_NODES) {
            int e0 = off[n] - lo, e1 = off[n + 1] - lo;
            int nb = (e1 - e0 + 3) >> 2;
            for (int bq = 0; bq < nb; ++bq) {
                int eb = e0 + bq * 4;
                int i0, i1, i2, i3;
                if (use_lds) {
                    i0 = EIdx[eb];
                    i1 = (eb + 1 < e1) ? EIdx[eb + 1] : N_NODES;
                    i2 = (eb + 2 < e1) ? EIdx[eb + 2] : N_NODES;
                    i3 = (eb + 3 < e1) ? EIdx[eb + 3] : N_NODES;
                } else {
                    i0 = esrc[lo + eb];
                    i1 = (eb + 1 < e1) ? esrc[lo + eb + 1] : N_NODES;
                    i2 = (eb + 2 < e1) ? esrc[lo + eb + 2] : N_NODES;
                    i3 = (eb + 3 < e1) ? esrc[lo + eb + 3] : N_NODES;
                }
                size_t s0 = (size_t)i0 * KP, s1 = (size_t)i1 * KP;
                size_t s2 = (size_t)i2 * KP, s3 = (size_t)i3 * KP;
                bfrag a0 = *(const bfrag*)(hcur + s0 + colA);
                bfrag a1 = *(const bfrag*)(hcur + s1 + colA);
                bfrag a2 = *(const bfrag*)(hcur + s2 + colA);
                bfrag a3 = *(const bfrag*)(hcur + s3 + colA);
                if (sumB) {
                    bfrag b0 = *(const bfrag*)(hcur + s0 + colB);
                    bfrag b1 = *(const bfrag*)(hcur + s1 + colB);
                    bfrag b2 = *(const bfrag*)(hcur + s2 + colB);
                    bfrag b3 = *(const bfrag*)(hcur + s3 + colB);
                    #pragma unroll
                    for (int q = 0; q < 8; ++q)
                        b[q] += (bf2f(b0[q]) + bf2f(b1[q])) + (bf2f(b2[q]) + bf2f(b3[q]));
                }
                #pragma unroll
                for (int q = 0; q < 8; ++q)
                    a[q] += (bf2f(a0[q]) + bf2f(a1[q])) + (bf2f(a2[q]) + bf2f(a3[q]));
            }
        }
        // pack + store (unconditional: rows >= N_NODES store zeros -> clean pad rows)
        __hip_bfloat16 oa[8], ob[8];
        #pragma unroll
        for (int q = 0; q < 8; ++q) {
            oa[q] = __float2bfloat16(a[q]);
            ob[q] = __float2bfloat16(b[q]);
        }
        __hip_bfloat16* arow = Ascr + (size_t)n * KP;
        *(ushort4*)(arow + colA)     = *(const ushort4*)&oa[0];
        *(ushort4*)(arow + colA + 4) = *(const ushort4*)&oa[4];
        if (ck < 12) {   // cols 128..223; cols 200..223 get zeros (b stayed 0)
            *(ushort4*)(arow + colB)     = *(const ushort4*)&ob[0];
            *(ushort4*)(arow + colB + 4) = *(const ushort4*)&ob[4];
        }
    }
}

// ---------------- MFMA GRU (+ pool on last step) ----------------
// v9 ROUND-COUNT FIX: gemm dur is invariant to grid/residency/de-phasing and equals
// 26 rounds x ~4.75us -> fixed per-round overhead (barrier + vmcnt(0) DMA-drain +
// 12-wave straggler jitter) dominates 15x over round compute. This version stages one
// FULL jt tile (gi+gh, 38912 B) per round -> 13 rounds, 2x compute per barrier.
// LDS: 2x38912 + 832 = 78.7 KB (gfx950 allows 160 KB static; HK template uses 128 KB)
// -> 2 blocks/CU, which v5-vs-v6 proved is perf-neutral for this kernel.
// Model: T = nF + C, F~4.3us, C~11us -> predict ~67us.
__global__ __launch_bounds__(256, 2) void gemm_gru(const __hip_bfloat16* __restrict__ hcur,
                                                   const __hip_bfloat16* __restrict__ Ascr,
                                                   __hip_bfloat16* __restrict__ hnext,
                                                   unsigned int* __restrict__ pooled,
                                                   int step) {
    __shared__ __align__(16) short Bs[2][FULL_SHORTS];  // 77824 B, weights only
    __shared__ unsigned int pmax[DP];                   // 832 B
    int tid = threadIdx.x;
    int lane = tid & 63, wave = tid >> 6;
    int mrow = lane & 15, kq = lane >> 4;
    int jcol = lane & 15;
    int rowq = (lane >> 4) * 4;
    bool dopool = (step == NUM_STEPS - 1);

    if (dopool) for (int c = tid; c < DP; c += 256) pmax[c] = 0u;

    const short* Wstep = g_Wall + (size_t)step * 13 * (2 * HALF_SHORTS);
    int wbase = blockIdx.x * 128 + wave * 32;
    int phase = blockIdx.x % 13;            // de-phase: starting jt differs per block

    // round index r (0..12) -> rotated jt-tile base address
    auto jtptr = [&](int r) {
        int q = phase + r; if (q >= 13) q -= 13;
        return Wstep + (size_t)(2 * q) * HALF_SHORTS;
    };

    stage_full(jtptr(0), &Bs[0][0], wave, lane);   // issue first jt-tile DMA ASAP

    // ---- A fragments from Ascr (direct, fragment-layout-contiguous) ----
    bfrag av[2][7], hv[2][7];
    #pragma unroll
    for (int p = 0; p < 2; ++p) {
        const __hip_bfloat16* arow = Ascr + (size_t)(wbase + p * 16 + mrow) * KP;
        #pragma unroll
        for (int t = 0; t < 7; ++t)
            av[p][t] = *(const bfrag*)(arow + t * 32 + kq * 8);
    }
    // ---- H fragments (resident; cols 200..223 are zero by construction) ----
    const __hip_bfloat16* hrow0 = hcur + (size_t)(wbase + mrow) * KP;
    const __hip_bfloat16* hrow1 = hrow0 + (size_t)16 * KP;
    #pragma unroll
    for (int t = 0; t < 7; ++t) {
        hv[0][t] = *(const bfrag*)(hrow0 + t * 32 + kq * 8);
        hv[1][t] = *(const bfrag*)(hrow1 + t * 32 + kq * 8);
    }

    // acc[0]=r (gi+gh), acc[1]=z (gi+gh), acc[2]=i_n, acc[3]=h_n
    facc acc[4][2];
    unsigned short hold_u[2][4];

    for (int r = 0; r < 13; ++r) {
        __syncthreads();   // tile r DMA complete; buf[(r+1)&1] free for restage
        if (r + 1 < 13)
            stage_full(jtptr(r + 1), &Bs[(r + 1) & 1][0], wave, lane);

        int jt = phase + r; if (jt >= 13) jt -= 13;
        int j = jt * 16 + jcol;
        const short* Bgi = &Bs[r & 1][0];
        const short* Bgh = Bgi + HALF_SHORTS;

        // preload old-h for this jt's epilogue (latency hides under gi+gh compute)
        #pragma unroll
        for (int mf = 0; mf < 2; ++mf)
            #pragma unroll
            for (int q = 0; q < 4; ++q)
                hold_u[mf][q] = *(const unsigned short*)
                    (hcur + (size_t)(wbase + mf * 16 + rowq + q) * KP + j);
        #pragma unroll
        for (int g = 0; g < 4; ++g)
            #pragma unroll
            for (int mf = 0; mf < 2; ++mf) acc[g][mf] = (facc)(0.0f);

        // gi gates (r,z,n_i) consume av -> acc 0,1,2
        #pragma unroll
        for (int t = 0; t < 7; ++t) {
            bfrag bv[3];
            #pragma unroll
            for (int g = 0; g < 3; ++g) bv[g] = bv_load(Bgi, g, t, lane);
            #pragma unroll
            for (int g = 0; g < 3; ++g)
                #pragma unroll
                for (int mf = 0; mf < 2; ++mf)
                    acc[g][mf] = __builtin_amdgcn_mfma_f32_16x16x32_bf16(av[mf][t], bv[g], acc[g][mf], 0, 0, 0);
        }
        // gh gates (r,z,n_h) consume hv -> acc 0,1 (merged) and 3
        #pragma unroll
        for (int t = 0; t < 7; ++t) {
            bfrag bv[3];
            #pragma unroll
            for (int g = 0; g < 3; ++g) bv[g] = bv_load(Bgh, g, t, lane);
            #pragma unroll
            for (int mf = 0; mf < 2; ++mf) {
                acc[0][mf] = __builtin_amdgcn_mfma_f32_16x16x32_bf16(hv[mf][t], bv[0], acc[0][mf], 0, 0, 0);
                acc[1][mf] = __builtin_amdgcn_mfma_f32_16x16x32_bf16(hv[mf][t], bv[1], acc[1][mf], 0, 0, 0);
                acc[3][mf] = __builtin_amdgcn_mfma_f32_16x16x32_bf16(hv[mf][t], bv[2], acc[3][mf], 0, 0, 0);
            }
        }

        // epilogue: C/D layout col=lane&15 (j), row=(lane>>4)*4+reg (m)
        float tmax = 0.0f;
        if (j < D) {
            float bir = g_bias[j],          biz = g_bias[DP + j],     bin = g_bias[2 * DP + j];
            float bhr = g_bias[3 * DP + j], bhz = g_bias[4 * DP + j], bhn = g_bias[5 * DP + j];
            #pragma unroll
            for (int mf = 0; mf < 2; ++mf) {
                int m0 = wbase + mf * 16 + rowq;
                #pragma unroll
                for (int q = 0; q < 4; ++q) {
                    int m = m0 + q;
                    if (m < N_NODES) {
                        float hold = bf2f((short)hold_u[mf][q]);
                        float rr = fast_sigmoid(acc[0][mf][q] + bir + bhr);
                        float zz = fast_sigmoid(acc[1][mf][q] + biz + bhz);
                        float nn = fast_tanh(acc[2][mf][q] + bin + rr * (acc[3][mf][q] + bhn));
                        float hv2 = (1.0f - zz) * nn + zz * hold;
                        hnext[(size_t)m * KP + j] = __float2bfloat16(hv2);
                        if (hv2 > tmax) tmax = hv2;
                    }
                }
            }
            if (dopool) atomicMax(&pmax[j], __float_as_uint(tmax));
        }
    }

    if (dopool) {
        __syncthreads();
        for (int c = tid; c < D; c += 256) atomicMax(&pooled[c], pmax[c]);
    }
}

// ---------------- logits + softmax ----------------
__global__ void head_kernel(const unsigned int* __restrict__ pooled,
                            const float* __restrict__ cls_w,
                            const float* __restrict__ cls_b,
                            float* __restrict__ out) {
    if (threadIdx.x == 0) {
        float l0 = cls_b[0], l1 = cls_b[1];
        for (int d = 0; d < D; ++d) {
            float p = __uint_as_float(pooled[d]);
            l0 += p * cls_w[d];
            l1 += p * cls_w[D + d];
        }
        float mx = l0 > l1 ? l0 : l1;
        float e0 = expf(l0 - mx), e1 = expf(l1 - mx);
        out[0] = e0 / (e0 + e1);
        out[1] = e1 / (e0 + e1);
    }
}

extern "C" void kernel_launch(void* const* d_in, const int* in_sizes, int n_in,
                              void* d_out, int out_size, void* d_ws, size_t ws_size,
                              hipStream_t stream) {
    const float* x     = (const float*)d_in[0];
    const float* W     = (const float*)d_in[1];
    const float* w_ih  = (const float*)d_in[2];
    const float* w_hh  = (const float*)d_in[3];
    const float* b_ih  = (const float*)d_in[4];
    const float* b_hh  = (const float*)d_in[5];
    const float* cls_w = (const float*)d_in[6];
    const float* cls_b = (const float*)d_in[7];
    const int*   ei    = (const int*)d_in[8];
    const int* src = ei;
    const int* dst = ei + N_EDGES;

    const size_t ROWB = (size_t)N_PAD * KP;     // bf16 elements per buffer
    __hip_bfloat16* hA   = (__hip_bfloat16*)d_ws;
    __hip_bfloat16* hB   = hA + ROWB;
    __hip_bfloat16* Ascr = hB + ROWB;           // aggregated-message scratch (3rd buffer)
    int* cnt    = (int*)(Ascr + ROWB);
    int* incl   = cnt + N_NODES;
    int* bsum   = incl + N_NODES;
    int* off    = bsum + 128;
    int* cursor = off + N_NODES + 1;
    int* esrc   = cursor + N_NODES;
    unsigned int* pooled = (unsigned int*)(esrc + N_EDGES);

    // CSR build (once per call; edges are step-invariant)
    hipMemsetAsync(cnt, 0, N_NODES * sizeof(int), stream);
    count_kernel<<<(N_EDGES + 255) / 256, 256, 0, stream>>>(dst, cnt);
    scan1<<<NB_SCAN, SCAN_B, 0, stream>>>(cnt, incl, bsum);
    scan3<<<(N_NODES + 255) / 256, 256, 0, stream>>>(cnt, incl, bsum, off, cursor);
    fill_kernel<<<(N_EDGES + 255) / 256, 256, 0, stream>>>(src, dst, cursor, esrc);

    // weight prep (one kernel: fragment permute + Wc fold + bias)
    wconv_kernel<<<WCONV_BLOCKS + 5, 256, 0, stream>>>(W, w_ih, w_hh, b_ih, b_hh);

    pad_kernel<<<(int)(ROWB / 256), 256, 0, stream>>>(x, hA);
    // hB fully zeroed once: (a) gather's clamped batches read zero-row N_NODES on
    // odd steps, (b) cols 200..223 stay zero forever -> hv t=6 is a plain load.
    hipMemsetAsync(hB, 0, ROWB * sizeof(__hip_bfloat16), stream);
    hipMemsetAsync(pooled, 0, D * sizeof(unsigned int), stream);

    __hip_bfloat16* hcur = hA;
    __hip_bfloat16* hnext = hB;
    for (int s = 0; s < NUM_STEPS; ++s) {
        gather_kernel<<<N_PAD / 32, 256, 0, stream>>>(hcur, Ascr, off, esrc);
        gemm_gru<<<N_PAD / 128, 256, 0, stream>>>(hcur, Ascr, hnext, pooled, s);
        __hip_bfloat16* t = hcur; hcur = hnext; hnext = t;
    }
    head_kernel<<<1, 64, 0, stream>>>(pooled, cls_w, cls_b, (float*)d_out);
}

// Round 11
// 830.679 us; speedup vs baseline: 1.5269x; 1.0019x over previous
//
#include <hip/hip_runtime.h>
#include <hip/hip_bf16.h>
#include <math.h>

#define N_NODES 100000
#define N_PAD   100096   // multiple of 256
#define N_EDGES 400000
#define IN_DIM  100
#define D       200
#define DP      208      // j padded to 13*16
#define KP      224      // k padded to 7*32
#define NUM_STEPS 4

// Truncated half-tile: 3 gates x (6 full t-blocks * 512 + t6 kq0 slice 128) = 9600
// shorts + 128 pad shorts (1216 x 16B chunks). A FULL jt tile = gi half + gh half.
#define HALF_SHORTS   9728
#define FULL_SHORTS   (2 * HALF_SHORTS)   // 19456 shorts = 38912 B
#define STAGE_GROUPS_FULL 38              // 19456 shorts / (64 lanes * 8 shorts)
#define GCAP          512          // per-wave edge-index LDS capacity in gather kernel
#define WCHUNKS_PER_SJT 2432       // 2 halves * 1216 chunks
#define WCONV_BLOCKS  494          // 4*13*2432 / 256

#define GRU_WAVES    8             // 512-thread gemm blocks: 8 waves x 32 rows = 256 rows
#define GRU_GRID     (N_PAD / 256) // 391 blocks, exact

typedef __attribute__((ext_vector_type(8))) short bfrag;   // 8 bf16 (4 VGPRs)
typedef __attribute__((ext_vector_type(4))) float facc;    // 4 fp32

// weights, per-(step,jt) contiguous TRUNCATED tile: [s][jt][half2][gg3][t-compact]
__device__ short g_Wall[NUM_STEPS * 13 * 2 * HALF_SHORTS];
__device__ float g_bias[6 * DP];

__device__ __forceinline__ float fast_sigmoid(float x) {
    return __builtin_amdgcn_rcpf(1.0f + __expf(-x));
}
__device__ __forceinline__ float fast_tanh(float x) {
    return 2.0f * __builtin_amdgcn_rcpf(1.0f + __expf(-2.0f * x)) - 1.0f;
}
__device__ __forceinline__ float bf2f(short u) {
    unsigned int x = ((unsigned int)(unsigned short)u) << 16;
    return __uint_as_float(x);
}

// ---------------- weight permute + Wc-fold + bias, all in one kernel ----------------
// Compact layout per (s,jt,half): gate gg in 0..2 at gg*3200 shorts:
//   t<6: gg*3200 + t*512 + lane*8      (lane 0..63)
//   t=6: gg*3200 + 3072 + l*8          (l 0..15, kq=0 slice only; k>=200 is dead: A-side zero)
// chunks 1200..1215 of each half are zero padding.
__global__ __launch_bounds__(256) void wconv_kernel(const float* __restrict__ W,
                                                    const float* __restrict__ w_ih,
                                                    const float* __restrict__ w_hh,
                                                    const float* __restrict__ b_ih,
                                                    const float* __restrict__ b_hh) {
    if (blockIdx.x >= WCONV_BLOCKS) {
        int idx = (blockIdx.x - WCONV_BLOCKS) * 256 + threadIdx.x;
        if (idx < 6 * DP) {
            int g = idx / DP, j = idx % DP;
            float v = 0.0f;
            if (j < D) v = (g < 3) ? b_ih[g * 200 + j] : b_hh[(g - 3) * 200 + j];
            g_bias[idx] = v;
        }
        return;
    }
    int idx = blockIdx.x * 256 + threadIdx.x;   // chunk id < 4*13*2432 = 126464
    short* out = g_Wall + (size_t)idx * 8;
    int s    = idx / (13 * WCHUNKS_PER_SJT);
    int rem  = idx % (13 * WCHUNKS_PER_SJT);
    int jt   = rem / WCHUNKS_PER_SJT;
    int r2   = rem % WCHUNKS_PER_SJT;
    int half = r2 / 1216;
    int c    = r2 % 1216;
    if (c >= 1200) {                       // pad chunks: store zeros
        #pragma unroll
        for (int i = 0; i < 8; ++i) out[i] = 0;
        return;
    }
    int gg = c / 400, cc = c % 400;
    int t  = (cc < 384) ? (cc >> 6) : 6;
    int l  = (cc < 384) ? (cc & 63) : (cc - 384);
    int g  = half * 3 + gg;
    int j  = jt * 16 + (l & 15);
    int k0 = t * 32 + (l >> 4) * 8;
    float vals[8];
    if (g < 3) {
        // fold: vals[i] = dot(w_ih[g*200+j], W[s][k0+i])
        const float* wr = (j < D) ? &w_ih[(size_t)(g * 200 + j) * D] : nullptr;
        #pragma unroll
        for (int i = 0; i < 8; ++i) vals[i] = 0.0f;
        if (wr) {
            #pragma unroll
            for (int i = 0; i < 8; ++i) {
                int k = k0 + i;
                if (k < D) {
                    const float* Wr = &W[(size_t)s * D * D + (size_t)k * D];
                    float acc = 0.0f;
                    #pragma unroll 4
                    for (int tt = 0; tt < D; ++tt) acc += wr[tt] * Wr[tt];
                    vals[i] = acc;
                }
            }
        }
    } else {
        #pragma unroll
        for (int i = 0; i < 8; ++i) {
            int k = k0 + i;
            vals[i] = (j < D && k < D) ? w_hh[((size_t)(g - 3) * 200 + j) * D + k] : 0.0f;
        }
    }
    #pragma unroll
    for (int i = 0; i < 8; ++i) {
        __hip_bfloat16 b = __float2bfloat16(vals[i]);
        out[i] = *reinterpret_cast<short*>(&b);
    }
}

// ---------------- pad: h[:, :100] = bf16(x), rest 0 ----------------
__global__ void pad_kernel(const float* __restrict__ x, __hip_bfloat16* __restrict__ h) {
    int idx = blockIdx.x * 256 + threadIdx.x;   // N_PAD*KP exact multiple of 256
    int n = idx / KP, c = idx % KP;
    float v = (n < N_NODES && c < IN_DIM) ? x[n * IN_DIM + c] : 0.0f;
    h[idx] = __float2bfloat16(v);
}

// ---------------- CSR build ----------------
__global__ void count_kernel(const int* __restrict__ dst, int* __restrict__ cnt) {
    int e = blockIdx.x * blockDim.x + threadIdx.x;
    if (e < N_EDGES) atomicAdd(&cnt[dst[e]], 1);
}

#define SCAN_B 1024
#define NB_SCAN ((N_NODES + SCAN_B - 1) / SCAN_B)   // 98
__global__ __launch_bounds__(SCAN_B) void scan1(const int* __restrict__ cnt,
                                                int* __restrict__ incl, int* __restrict__ bsum) {
    __shared__ int ws[16];
    int i = blockIdx.x * SCAN_B + threadIdx.x;
    int lane = threadIdx.x & 63, wid = threadIdx.x >> 6;
    int v = (i < N_NODES) ? cnt[i] : 0;
    int s = v;
    #pragma unroll
    for (int o = 1; o < 64; o <<= 1) {
        int t = __shfl_up(s, o, 64);
        if (lane >= o) s += t;
    }
    if (lane == 63) ws[wid] = s;
    __syncthreads();
    if (wid == 0) {
        int t = (lane < 16) ? ws[lane] : 0;
        #pragma unroll
        for (int o = 1; o < 16; o <<= 1) {
            int u = __shfl_up(t, o, 64);
            if (lane >= o) t += u;
        }
        if (lane < 16) ws[lane] = t;
    }
    __syncthreads();
    if (wid > 0) s += ws[wid - 1];
    if (i < N_NODES) incl[i] = s;
    if (threadIdx.x == SCAN_B - 1) bsum[blockIdx.x] = s;
}
__global__ void scan3(const int* __restrict__ cnt, const int* __restrict__ incl,
                      const int* __restrict__ bsum, int* __restrict__ off,
                      int* __restrict__ cursor) {
    __shared__ int sh[128];
    if (threadIdx.x < 128) sh[threadIdx.x] = (threadIdx.x < NB_SCAN) ? bsum[threadIdx.x] : 0;
    __syncthreads();
    for (int o = 1; o < 128; o <<= 1) {
        int t = (threadIdx.x >= o && threadIdx.x < 128) ? sh[threadIdx.x - o] : 0;
        __syncthreads();
        if (threadIdx.x < 128) sh[threadIdx.x] += t;
        __syncthreads();
    }
    int i = blockIdx.x * blockDim.x + threadIdx.x;
    if (i < N_NODES) {
        int b = i / SCAN_B;
        int pre = b ? sh[b - 1] : 0;
        int v = incl[i] - cnt[i] + pre;
        off[i] = v; cursor[i] = v;
    }
    if (i == 0) off[N_NODES] = N_EDGES;
}
__global__ void fill_kernel(const int* __restrict__ src, const int* __restrict__ dst,
                            int* __restrict__ cursor, int* __restrict__ esrc) {
    int e = blockIdx.x * blockDim.x + threadIdx.x;
    if (e < N_EDGES) {
        int pos = atomicAdd(&cursor[dst[e]], 1);
        esrc[pos] = src[e];
    }
}

// ---------------- async stage: one FULL jt tile (38912 B) global -> LDS ----------------
// striped across NW waves
__device__ __forceinline__ void stage_full(const short* __restrict__ gsrc,
                                           short* lds_dst, int wave, int lane, int nw) {
    for (int g = wave; g < STAGE_GROUPS_FULL; g += nw) {
        __builtin_amdgcn_global_load_lds(
            (const __attribute__((address_space(1))) void*)(gsrc + g * 512 + lane * 8),
            (__attribute__((address_space(3))) void*)(lds_dst + g * 512),
            16, 0, 0);
    }
}

// B-fragment read from a truncated staged half (base = gi half or gh half).
// t is compile-time (unrolled loops). t=6, lanes kq>=1: k>=200 where A-side is
// structurally zero -> supply zeros (NaN-safe).
__device__ __forceinline__ bfrag bv_load(const short* base, int g, int t, int lane) {
    if (t < 6) return *(const bfrag*)(base + g * 3200 + t * 512 + lane * 8);
    bfrag z;
    #pragma unroll
    for (int i = 0; i < 8; ++i) z[i] = 0;
    if (lane < 16) z = *(const bfrag*)(base + g * 3200 + 3072 + lane * 8);
    return z;
}

// ---------------- gather/aggregate kernel ----------------
// Latency/occupancy-bound (v3/v4 evidence: BW scales with resident waves). 8 rows
// per wave, grid 3128, GCAP 512 -> 8 KB LDS/block; streams through the 32-wave/CU cap.
__global__ __launch_bounds__(256) void gather_kernel(const __hip_bfloat16* __restrict__ hcur,
                                                     __hip_bfloat16* __restrict__ Ascr,
                                                     const int* __restrict__ off,
                                                     const int* __restrict__ esrc) {
    __shared__ int EIdxAll[4 * GCAP];   // 8192 B
    int tid = threadIdx.x;
    int lane = tid & 63, wave = tid >> 6;
    int wbase = blockIdx.x * 32 + wave * 8;
    int* EIdx = EIdxAll + wave * GCAP;

    // prefetch this wave's contiguous esrc slice (CSR rows are contiguous)
    int nlo = wbase < N_NODES ? wbase : N_NODES;
    int nhi = (wbase + 8) < N_NODES ? (wbase + 8) : N_NODES;
    int lo = off[nlo];
    int cntw = off[nhi] - lo;
    bool use_lds = (cntw <= GCAP);
    if (use_lds)
        for (int i = lane; i < cntw; i += 64) EIdx[i] = esrc[lo + i];

    int r4 = lane >> 4;              // row-in-flight 0..3
    int ck = lane & 15;              // 16B chunk id (this lane also covers ck+16)
    int colA = ck * 8;
    int colB = colA + 128;           // (ck+16)*8
    bool sumB = (ck < 9);            // chunks 16..24 carry data (cols < 200)
    #pragma unroll
    for (int it = 0; it < 2; ++it) {
        int rr = it * 4 + r4;
        int n = wbase + rr;
        float a[8] = {0, 0, 0, 0, 0, 0, 0, 0};
        float b[8] = {0, 0, 0, 0, 0, 0, 0, 0};
        if (n < N_NODES) {
            int e0 = off[n] - lo, e1 = off[n + 1] - lo;
            int nb = (e1 - e0 + 3) >> 2;
            for (int bq = 0; bq < nb; ++bq) {
                int eb = e0 + bq * 4;
                int i0, i1, i2, i3;
                if (use_lds) {
                    i0 = EIdx[eb];
                    i1 = (eb + 1 < e1) ? EIdx[eb + 1] : N_NODES;
                    i2 = (eb + 2 < e1) ? EIdx[eb + 2] : N_NODES;
                    i3 = (eb + 3 < e1) ? EIdx[eb + 3] : N_NODES;
                } else {
                    i0 = esrc[lo + eb];
                    i1 = (eb + 1 < e1) ? esrc[lo + eb + 1] : N_NODES;
                    i2 = (eb + 2 < e1) ? esrc[lo + eb + 2] : N_NODES;
                    i3 = (eb + 3 < e1) ? esrc[lo + eb + 3] : N_NODES;
                }
                size_t s0 = (size_t)i0 * KP, s1 = (size_t)i1 * KP;
                size_t s2 = (size_t)i2 * KP, s3 = (size_t)i3 * KP;
                bfrag a0 = *(const bfrag*)(hcur + s0 + colA);
                bfrag a1 = *(const bfrag*)(hcur + s1 + colA);
                bfrag a2 = *(const bfrag*)(hcur + s2 + colA);
                bfrag a3 = *(const bfrag*)(hcur + s3 + colA);
                if (sumB) {
                    bfrag b0 = *(const bfrag*)(hcur + s0 + colB);
                    bfrag b1 = *(const bfrag*)(hcur + s1 + colB);
                    bfrag b2 = *(const bfrag*)(hcur + s2 + colB);
                    bfrag b3 = *(const bfrag*)(hcur + s3 + colB);
                    #pragma unroll
                    for (int q = 0; q < 8; ++q)
                        b[q] += (bf2f(b0[q]) + bf2f(b1[q])) + (bf2f(b2[q]) + bf2f(b3[q]));
                }
                #pragma unroll
                for (int q = 0; q < 8; ++q)
                    a[q] += (bf2f(a0[q]) + bf2f(a1[q])) + (bf2f(a2[q]) + bf2f(a3[q]));
            }
        }
        // pack + store (unconditional: rows >= N_NODES store zeros -> clean pad rows)
        __hip_bfloat16 oa[8], ob[8];
        #pragma unroll
        for (int q = 0; q < 8; ++q) {
            oa[q] = __float2bfloat16(a[q]);
            ob[q] = __float2bfloat16(b[q]);
        }
        __hip_bfloat16* arow = Ascr + (size_t)n * KP;
        *(ushort4*)(arow + colA)     = *(const ushort4*)&oa[0];
        *(ushort4*)(arow + colA + 4) = *(const ushort4*)&oa[4];
        if (ck < 12) {   // cols 128..223; cols 200..223 get zeros (b stayed 0)
            *(ushort4*)(arow + colB)     = *(const ushort4*)&ob[0];
            *(ushort4*)(arow + colB + 4) = *(const ushort4*)&ob[4];
        }
    }
}

// ---------------- MFMA GRU (+ pool on last step) ----------------
// v10 STAGED-BYTES FIX: four experiments (v5/v6/v8/v9) pin an empirical invariant:
// gemm time = per-CU staged weight bytes / ~12.6 GB/s (v9: 2x bytes/round, half the
// rounds -> identical time; v6: 2x residency -> identical; v8: de-phase -> -2%).
// So the lever is staged bytes per CU: this version covers 256 rows per block
// (512 threads, 8 waves x 32 rows, grid 391) -> the 506 KB weight stream is staged
// half as many times -> per-CU staged bytes 1.54 MB -> 0.77 MB -> predict ~65-80us.
// Per-wave state is UNCHANGED from the verified 112-VGPR config (av[2][7], hv[2][7],
// acc[4][2], 32 rows/wave); only wave count and grid change. LDS 78.7 KB -> 2
// blocks/CU (16 waves). (512,2) keeps the proven 256-reg budget (no remat trap).
__global__ __launch_bounds__(512, 2) void gemm_gru(const __hip_bfloat16* __restrict__ hcur,
                                                   const __hip_bfloat16* __restrict__ Ascr,
                                                   __hip_bfloat16* __restrict__ hnext,
                                                   unsigned int* __restrict__ pooled,
                                                   int step) {
    __shared__ __align__(16) short Bs[2][FULL_SHORTS];  // 77824 B, weights only
    __shared__ unsigned int pmax[DP];                   // 832 B
    int tid = threadIdx.x;
    int lane = tid & 63, wave = tid >> 6;               // wave 0..7
    int mrow = lane & 15, kq = lane >> 4;
    int jcol = lane & 15;
    int rowq = (lane >> 4) * 4;
    bool dopool = (step == NUM_STEPS - 1);

    if (dopool) for (int c = tid; c < DP; c += 512) pmax[c] = 0u;

    const short* Wstep = g_Wall + (size_t)step * 13 * (2 * HALF_SHORTS);
    int wbase = blockIdx.x * 256 + wave * 32;
    int phase = blockIdx.x % 13;            // de-phase: starting jt differs per block

    // round index r (0..12) -> rotated jt-tile base address
    auto jtptr = [&](int r) {
        int q = phase + r; if (q >= 13) q -= 13;
        return Wstep + (size_t)(2 * q) * HALF_SHORTS;
    };

    stage_full(jtptr(0), &Bs[0][0], wave, lane, GRU_WAVES);   // first jt-tile DMA ASAP

    // ---- A fragments from Ascr (direct, fragment-layout-contiguous) ----
    bfrag av[2][7], hv[2][7];
    #pragma unroll
    for (int p = 0; p < 2; ++p) {
        const __hip_bfloat16* arow = Ascr + (size_t)(wbase + p * 16 + mrow) * KP;
        #pragma unroll
        for (int t = 0; t < 7; ++t)
            av[p][t] = *(const bfrag*)(arow + t * 32 + kq * 8);
    }
    // ---- H fragments (resident; cols 200..223 are zero by construction) ----
    const __hip_bfloat16* hrow0 = hcur + (size_t)(wbase + mrow) * KP;
    const __hip_bfloat16* hrow1 = hrow0 + (size_t)16 * KP;
    #pragma unroll
    for (int t = 0; t < 7; ++t) {
        hv[0][t] = *(const bfrag*)(hrow0 + t * 32 + kq * 8);
        hv[1][t] = *(const bfrag*)(hrow1 + t * 32 + kq * 8);
    }

    // acc[0]=r (gi+gh), acc[1]=z (gi+gh), acc[2]=i_n, acc[3]=h_n
    facc acc[4][2];
    unsigned short hold_u[2][4];

    for (int r = 0; r < 13; ++r) {
        __syncthreads();   // tile r DMA complete; buf[(r+1)&1] free for restage
        if (r + 1 < 13)
            stage_full(jtptr(r + 1), &Bs[(r + 1) & 1][0], wave, lane, GRU_WAVES);

        int jt = phase + r; if (jt >= 13) jt -= 13;
        int j = jt * 16 + jcol;
        const short* Bgi = &Bs[r & 1][0];
        const short* Bgh = Bgi + HALF_SHORTS;

        // preload old-h for this jt's epilogue (latency hides under gi+gh compute)
        #pragma unroll
        for (int mf = 0; mf < 2; ++mf)
            #pragma unroll
            for (int q = 0; q < 4; ++q)
                hold_u[mf][q] = *(const unsigned short*)
                    (hcur + (size_t)(wbase + mf * 16 + rowq + q) * KP + j);
        #pragma unroll
        for (int g = 0; g < 4; ++g)
            #pragma unroll
            for (int mf = 0; mf < 2; ++mf) acc[g][mf] = (facc)(0.0f);

        // gi gates (r,z,n_i) consume av -> acc 0,1,2
        #pragma unroll
        for (int t = 0; t < 7; ++t) {
            bfrag bv[3];
            #pragma unroll
            for (int g = 0; g < 3; ++g) bv[g] = bv_load(Bgi, g, t, lane);
            #pragma unroll
            for (int g = 0; g < 3; ++g)
                #pragma unroll
                for (int mf = 0; mf < 2; ++mf)
                    acc[g][mf] = __builtin_amdgcn_mfma_f32_16x16x32_bf16(av[mf][t], bv[g], acc[g][mf], 0, 0, 0);
        }
        // gh gates (r,z,n_h) consume hv -> acc 0,1 (merged) and 3
        #pragma unroll
        for (int t = 0; t < 7; ++t) {
            bfrag bv[3];
            #pragma unroll
            for (int g = 0; g < 3; ++g) bv[g] = bv_load(Bgh, g, t, lane);
            #pragma unroll
            for (int mf = 0; mf < 2; ++mf) {
                acc[0][mf] = __builtin_amdgcn_mfma_f32_16x16x32_bf16(hv[mf][t], bv[0], acc[0][mf], 0, 0, 0);
                acc[1][mf] = __builtin_amdgcn_mfma_f32_16x16x32_bf16(hv[mf][t], bv[1], acc[1][mf], 0, 0, 0);
                acc[3][mf] = __builtin_amdgcn_mfma_f32_16x16x32_bf16(hv[mf][t], bv[2], acc[3][mf], 0, 0, 0);
            }
        }

        // epilogue: C/D layout col=lane&15 (j), row=(lane>>4)*4+reg (m)
        float tmax = 0.0f;
        if (j < D) {
            float bir = g_bias[j],          biz = g_bias[DP + j],     bin = g_bias[2 * DP + j];
            float bhr = g_bias[3 * DP + j], bhz = g_bias[4 * DP + j], bhn = g_bias[5 * DP + j];
            #pragma unroll
            for (int mf = 0; mf < 2; ++mf) {
                int m0 = wbase + mf * 16 + rowq;
                #pragma unroll
                for (int q = 0; q < 4; ++q) {
                    int m = m0 + q;
                    if (m < N_NODES) {
                        float hold = bf2f((short)hold_u[mf][q]);
                        float rr = fast_sigmoid(acc[0][mf][q] + bir + bhr);
                        float zz = fast_sigmoid(acc[1][mf][q] + biz + bhz);
                        float nn = fast_tanh(acc[2][mf][q] + bin + rr * (acc[3][mf][q] + bhn));
                        float hv2 = (1.0f - zz) * nn + zz * hold;
                        hnext[(size_t)m * KP + j] = __float2bfloat16(hv2);
                        if (hv2 > tmax) tmax = hv2;
                    }
                }
            }
            if (dopool) atomicMax(&pmax[j], __float_as_uint(tmax));
        }
    }

    if (dopool) {
        __syncthreads();
        for (int c = tid; c < D; c += 512) atomicMax(&pooled[c], pmax[c]);
    }
}

// ---------------- logits + softmax ----------------
__global__ void head_kernel(const unsigned int* __restrict__ pooled,
                            const float* __restrict__ cls_w,
                            const float* __restrict__ cls_b,
                            float* __restrict__ out) {
    if (threadIdx.x == 0) {
        float l0 = cls_b[0], l1 = cls_b[1];
        for (int d = 0; d < D; ++d) {
            float p = __uint_as_float(pooled[d]);
            l0 += p * cls_w[d];
            l1 += p * cls_w[D + d];
        }
        float mx = l0 > l1 ? l0 : l1;
        float e0 = expf(l0 - mx), e1 = expf(l1 - mx);
        out[0] = e0 / (e0 + e1);
        out[1] = e1 / (e0 + e1);
    }
}

extern "C" void kernel_launch(void* const* d_in, const int* in_sizes, int n_in,
                              void* d_out, int out_size, void* d_ws, size_t ws_size,
                              hipStream_t stream) {
    const float* x     = (const float*)d_in[0];
    const float* W     = (const float*)d_in[1];
    const float* w_ih  = (const float*)d_in[2];
    const float* w_hh  = (const float*)d_in[3];
    const float* b_ih  = (const float*)d_in[4];
    const float* b_hh  = (const float*)d_in[5];
    const float* cls_w = (const float*)d_in[6];
    const float* cls_b = (const float*)d_in[7];
    const int*   ei    = (const int*)d_in[8];
    const int* src = ei;
    const int* dst = ei + N_EDGES;

    const size_t ROWB = (size_t)N_PAD * KP;     // bf16 elements per buffer
    __hip_bfloat16* hA   = (__hip_bfloat16*)d_ws;
    __hip_bfloat16* hB   = hA + ROWB;
    __hip_bfloat16* Ascr = hB + ROWB;           // aggregated-message scratch (3rd buffer)
    int* cnt    = (int*)(Ascr + ROWB);
    int* incl   = cnt + N_NODES;
    int* bsum   = incl + N_NODES;
    int* off    = bsum + 128;
    int* cursor = off + N_NODES + 1;
    int* esrc   = cursor + N_NODES;
    unsigned int* pooled = (unsigned int*)(esrc + N_EDGES);

    // CSR build (once per call; edges are step-invariant)
    hipMemsetAsync(cnt, 0, N_NODES * sizeof(int), stream);
    count_kernel<<<(N_EDGES + 255) / 256, 256, 0, stream>>>(dst, cnt);
    scan1<<<NB_SCAN, SCAN_B, 0, stream>>>(cnt, incl, bsum);
    scan3<<<(N_NODES + 255) / 256, 256, 0, stream>>>(cnt, incl, bsum, off, cursor);
    fill_kernel<<<(N_EDGES + 255) / 256, 256, 0, stream>>>(src, dst, cursor, esrc);

    // weight prep (one kernel: fragment permute + Wc fold + bias)
    wconv_kernel<<<WCONV_BLOCKS + 5, 256, 0, stream>>>(W, w_ih, w_hh, b_ih, b_hh);

    pad_kernel<<<(int)(ROWB / 256), 256, 0, stream>>>(x, hA);
    // hB fully zeroed once: (a) gather's clamped batches read zero-row N_NODES on
    // odd steps, (b) cols 200..223 stay zero forever -> hv t=6 is a plain load.
    hipMemsetAsync(hB, 0, ROWB * sizeof(__hip_bfloat16), stream);
    hipMemsetAsync(pooled, 0, D * sizeof(unsigned int), stream);

    __hip_bfloat16* hcur = hA;
    __hip_bfloat16* hnext = hB;
    for (int s = 0; s < NUM_STEPS; ++s) {
        gather_kernel<<<N_PAD / 32, 256, 0, stream>>>(hcur, Ascr, off, esrc);
        gemm_gru<<<GRU_GRID, 512, 0, stream>>>(hcur, Ascr, hnext, pooled, s);
        __hip_bfloat16* t = hcur; hcur = hnext; hnext = t;
    }
    head_kernel<<<1, 64, 0, stream>>>(pooled, cls_w, cls_b, (float*)d_out);
}